// Round 5
// baseline (577.506 us; speedup 1.0000x reference)
//
#include <hip/hip_runtime.h>
#include <stdint.h>

#define B_SZ 128
#define T_SZ 64
#define N_IN 1024
#define N_HID 4096
#define N_OUT 1024
#define TAU 0.9f
#define THRESH 0.5f
#define REC_SCALE 0.1f
#define S_DENSE 5          // steps 0..4 computed via dense MFMA GEMMs
#define KSPLIT 8           // K-split for spk GEMMs (4096/8 = 512 per chunk)

typedef __attribute__((ext_vector_type(8))) short sh8;
typedef __attribute__((ext_vector_type(4))) float f32x4;
typedef __attribute__((ext_vector_type(4))) int i32x4;
typedef __attribute__((ext_vector_type(4))) unsigned short ush4;
typedef __attribute__((ext_vector_type(8))) unsigned short ush8;

// ---------------------------------------------------------------------------
// helpers
// ---------------------------------------------------------------------------
__device__ __forceinline__ unsigned short f2bf_rn(float f) {
    unsigned u = __float_as_uint(f);
    unsigned r = (u + 0x7FFFu + ((u >> 16) & 1u)) >> 16;
    return (unsigned short)r;
}
__device__ __forceinline__ float bf2f(unsigned short h) {
    return __uint_as_float((unsigned)h << 16);
}
__device__ __forceinline__ void gload_lds16(const void* g, void* l) {
    __builtin_amdgcn_global_load_lds(
        (const __attribute__((address_space(1))) void*)g,
        (__attribute__((address_space(3))) void*)l, 16, 0, 0);
}
// compress low nibbles of 4 bytes into 16 bits
__device__ __forceinline__ unsigned pack4(unsigned a) {
    a &= 0x0F0F0F0Fu;
    a = (a | (a >> 4)) & 0x00FF00FFu;
    a = (a | (a >> 8)) & 0x0000FFFFu;
    return a;
}

// ---------------------------------------------------------------------------
__global__ void zero_state_kernel(float* p, int n) {
    int i = blockIdx.x * blockDim.x + threadIdx.x;
    int stride = gridDim.x * blockDim.x;
    for (; i < n; i += stride) p[i] = 0.0f;
}

// ---------------------------------------------------------------------------
// fused: W [R][C] fp32 -> WB [R][C] bf16 AND WT [C][R] bf16 (one read of W)
// ---------------------------------------------------------------------------
__global__ __launch_bounds__(256)
void convT_bf16_kernel(const float* __restrict__ W,
                       unsigned short* __restrict__ WB,
                       unsigned short* __restrict__ WT, int R, int C) {
    __shared__ float ts[64][65];
    int tid = threadIdx.x;
    int c0 = blockIdx.x * 64;
    int r0 = blockIdx.y * 64;
    #pragma unroll
    for (int rr = 0; rr < 16; ++rr) {
        int r = rr * 4 + (tid >> 6);
        int c = tid & 63;
        float v = W[(size_t)(r0 + r) * C + c0 + c];
        ts[r][c] = v;
        WB[(size_t)(r0 + r) * C + c0 + c] = f2bf_rn(v);
    }
    __syncthreads();
    #pragma unroll
    for (int rr = 0; rr < 16; ++rr) {
        int c = rr * 4 + (tid >> 6);
        int r = tid & 63;
        WT[(size_t)(c0 + c) * R + r0 + r] = f2bf_rn(ts[r][c]);
    }
}

// ---------------------------------------------------------------------------
// column sums of the bf16-rounded W_rec / W_out (for the sparse complement)
// ---------------------------------------------------------------------------
__global__ __launch_bounds__(256)
void colsum_bf16_kernel(const unsigned short* __restrict__ WrecB,
                        const unsigned short* __restrict__ WoutB,
                        float* __restrict__ cs_rec, float* __restrict__ cs_out) {
    __shared__ float part[4][64];
    int tid = threadIdx.x;
    int c = tid & 63, q = tid >> 6;
    int col = blockIdx.x * 64 + c;  // 0..5119
    float s = 0.f;
    if (col < N_HID) {
        const unsigned short* p = WrecB + col + (size_t)q * 1024 * N_HID;
        for (int j = 0; j < 1024; ++j) s += bf2f(p[(size_t)j * N_HID]);
    } else {
        int o = col - N_HID;
        const unsigned short* p = WoutB + o + (size_t)q * 1024 * N_OUT;
        for (int j = 0; j < 1024; ++j) s += bf2f(p[(size_t)j * N_OUT]);
    }
    part[q][c] = s;
    __syncthreads();
    if (tid < 64) {
        float tot = part[0][tid] + part[1][tid] + part[2][tid] + part[3][tid];
        int col2 = blockIdx.x * 64 + tid;
        if (col2 < N_HID) cs_rec[col2] = tot;
        else              cs_out[col2 - N_HID] = tot;
    }
}

// ---------------------------------------------------------------------------
// x [B,T,1024] fp32 -> Ax [128*Tc][2048] int8 limbs: cols 0..1023 = X1 (high
// 6 bits), 1024..2047 = X0 (low 7 bits); x ~= 2^-13 * (X1*128 + X0).
// 13-bit quantization keeps X1 <= 63 so the fc1 single-i32-acc chain
// (acc<<7 between segments) provably cannot overflow (max 1.08e9 < 2^31).
// ---------------------------------------------------------------------------
__global__ __launch_bounds__(256)
void convert_x_kernel(const float* __restrict__ x, char* __restrict__ Ax,
                      int t0, int Tc) {
    int total4 = B_SZ * Tc * (N_IN / 4);
    int i = blockIdx.x * blockDim.x + threadIdx.x;
    int stride = gridDim.x * blockDim.x;
    for (; i < total4; i += stride) {
        int m = i >> 8;
        int c4 = i & 255;
        int b = m / Tc, tl = m - b * Tc;
        float4 v = *(const float4*)(x + ((size_t)(b * T_SZ + t0 + tl) * N_IN) + c4 * 4);
        float f[4] = {v.x, v.y, v.z, v.w};
        char hi[4], lo[4];
        #pragma unroll
        for (int j = 0; j < 4; ++j) {
            int X = (int)rintf(f[j] * 8192.0f);
            X = X < 0 ? 0 : (X > 8191 ? 8191 : X);
            hi[j] = (char)(X >> 7);          // 0..63
            lo[j] = (char)(X & 127);         // 0..127
        }
        char* row = Ax + (size_t)m * 2048;
        *(char4*)(row + c4 * 4)        = *(const char4*)hi;
        *(char4*)(row + 1024 + c4 * 4) = *(const char4*)lo;
    }
}

// ---------------------------------------------------------------------------
// W_fc1 [1024][4096] fp32 -> Bt [4096][2048] int8 limbs, transposed:
// cols 0..1023 = V1, 1024..2047 = V0; W ~= 2^-19 * (V1*128 + V0).
// ---------------------------------------------------------------------------
__global__ __launch_bounds__(256)
void convert_w_kernel(const float* __restrict__ W, char* __restrict__ Bt) {
    __shared__ float ts[32][65];
    int tid = threadIdx.x;
    int k0 = blockIdx.x * 32;
    int n0 = blockIdx.y * 64;
    #pragma unroll
    for (int rr = 0; rr < 8; ++rr) {
        int kl = (tid >> 6) * 8 + rr;
        int nl = tid & 63;
        ts[kl][nl] = W[(size_t)(k0 + kl) * N_HID + n0 + nl];
    }
    __syncthreads();
    #pragma unroll
    for (int rr = 0; rr < 8; ++rr) {
        int nl = (tid >> 5) + rr * 8;
        int kl = tid & 31;
        float v = ts[kl][nl];
        int V = (int)rintf(v * 524288.0f);
        V = V < -16383 ? -16383 : (V > 16383 ? 16383 : V);
        char* row = Bt + (size_t)(n0 + nl) * 2048;
        row[k0 + kl]        = (char)(V >> 7);   // -128..127
        row[1024 + k0 + kl] = (char)(V & 127);  // 0..127
    }
}

// ---------------------------------------------------------------------------
// fc1 GEMM via int8 MFMA, virtual K = 3072 (X0*V0 dropped, sigma~2e-5):
//   iters  0..15:  X1 * V1      (then acc <<= 7 at iter 16)
//   iters 16..47:  [X1|X0] * [V0|V1] cross terms (bk = (ak+1024)&2047)
//   C = 2^-25 * (float)acc
// Row-major [128][64B] LDS tile, rotation-swizzled chunks (round-4 fix:
// coalesced staging + conflict-free reads), 2-phase double buffer, XCD-aware
// block swizzle. Unchanged from round 4 (150us, MfmaUtil 31%).
// ---------------------------------------------------------------------------
__global__ __launch_bounds__(256)
void fc1_mfma_kernel(const char* __restrict__ A,
                     const char* __restrict__ Bt,
                     float* __restrict__ C, int my) {
    __shared__ __attribute__((aligned(16))) char As[2][128 * 64];
    __shared__ __attribute__((aligned(16))) char Bs[2][128 * 64];
    const int tid = threadIdx.x;
    const int lane = tid & 63;
    const int wave = tid >> 6;
    const int wm = (wave >> 1) * 64;   // waves 2(M) x 2(N)
    const int wn = (wave & 1) * 64;
    const int quad = lane >> 4, l16 = lane & 15;

    // XCD swizzle: XCD k owns m-tiles [k*my/8, (k+1)*my/8), n varies outer.
    const int lin = blockIdx.x;
    const int ych = my >> 3;                 // my % 8 == 0 guaranteed
    const int xcd = lin & 7, rel = lin >> 3;
    const int m0 = (xcd * ych + (rel % ych)) * 128;
    const int n0 = (rel / ych) * 128;

    const char* aptr[2];
    const char* bptr[2];
    int loff[2];
    #pragma unroll
    for (int i = 0; i < 2; ++i) {
        int idx = i * 256 + tid;             // 0..511 -> row=idx>>2, ch=idx&3
        int row = idx >> 2, ch = idx & 3;
        int g = (ch - (row >> 1)) & 3;       // inverse rotation on global src
        aptr[i] = A  + (size_t)(m0 + row) * 2048 + g * 16;
        bptr[i] = Bt + (size_t)(n0 + row) * 2048 + g * 16;
        loff[i] = idx * 16;                  // linear LDS dest (DMA constraint)
    }

    i32x4 acc[4][4] = {};

    // prologue: stage iter 0 (ak=0, bk=0) into buffer 0
    gload_lds16(aptr[0], &As[0][loff[0]]);
    gload_lds16(aptr[1], &As[0][loff[1]]);
    gload_lds16(bptr[0], &Bs[0][loff[0]]);
    gload_lds16(bptr[1], &Bs[0][loff[1]]);
    __syncthreads();

    int cur = 0;
    for (int kt = 0; kt < 48; ++kt) {
        // issue next tile's loads into the other buffer (before compute)
        if (kt + 1 < 48) {
            int kn = kt + 1;
            int ak = (kn < 16 ? kn : kn - 16) * 64;
            int bk = (kn < 16) ? ak : ((ak + 1024) & 2047);
            int nxt = cur ^ 1;
            gload_lds16(aptr[0] + ak, &As[nxt][loff[0]]);
            gload_lds16(aptr[1] + ak, &As[nxt][loff[1]]);
            gload_lds16(bptr[0] + bk, &Bs[nxt][loff[0]]);
            gload_lds16(bptr[1] + bk, &Bs[nxt][loff[1]]);
        }
        // segment boundary: scale hi-limb partial by 128 (exact)
        if (kt == 16) {
            #pragma unroll
            for (int mt = 0; mt < 4; ++mt)
                #pragma unroll
                for (int nt = 0; nt < 4; ++nt)
                    #pragma unroll
                    for (int r = 0; r < 4; ++r)
                        acc[mt][nt][r] <<= 7;
        }
        // compute current buffer (rotated chunk addressing)
        const char* ca = As[cur];
        const char* cb = Bs[cur];
        i32x4 af[4], bf[4];
        #pragma unroll
        for (int mt = 0; mt < 4; ++mt) {
            int row = wm + mt * 16 + l16;
            int c = (quad + (row >> 1)) & 3;
            af[mt] = *(const i32x4*)&ca[row * 64 + c * 16];
        }
        #pragma unroll
        for (int nt = 0; nt < 4; ++nt) {
            int row = wn + nt * 16 + l16;
            int c = (quad + (row >> 1)) & 3;
            bf[nt] = *(const i32x4*)&cb[row * 64 + c * 16];
        }
        #pragma unroll
        for (int mt = 0; mt < 4; ++mt)
            #pragma unroll
            for (int nt = 0; nt < 4; ++nt)
                acc[mt][nt] = __builtin_amdgcn_mfma_i32_16x16x64_i8(
                    af[mt], bf[nt], acc[mt][nt], 0, 0, 0);
        __syncthreads();
        cur ^= 1;
    }

    #pragma unroll
    for (int mt = 0; mt < 4; ++mt)
        #pragma unroll
        for (int nt = 0; nt < 4; ++nt) {
            int col = n0 + wn + nt * 16 + l16;
            #pragma unroll
            for (int r = 0; r < 4; ++r) {
                int m = m0 + wm + mt * 16 + quad * 4 + r;
                C[(size_t)m * N_HID + col] = 0x1p-25f * (float)acc[mt][nt][r];
            }
        }
}

// ---------------------------------------------------------------------------
// One 128x128 C-tile of part[ks][128][Nfull] = spk[128][4096] @ BT[...]^T over
// a 512-wide K chunk. Rotation-swizzled staging/read, 2-phase double buffer.
// ---------------------------------------------------------------------------
__device__ __forceinline__ void spk_tile_gemm(const unsigned short* __restrict__ A,
                                              const unsigned short* __restrict__ BT,
                                              float* __restrict__ part, int Nfull,
                                              int nt, int ks,
                                              unsigned short (*As)[128 * 32],
                                              unsigned short (*Bs)[128 * 32],
                                              int tid) {
    const int lane = tid & 63;
    const int wave = tid >> 6;
    const int wm = (wave >> 1) * 64;
    const int wn = (wave & 1) * 64;
    const int quad = lane >> 4, l16 = lane & 15;
    const int n0 = nt * 128;
    const int k0 = ks * (N_HID / KSPLIT);

    const unsigned short* aptr[2];
    const unsigned short* bptr[2];
    int loff[2];
    #pragma unroll
    for (int i = 0; i < 2; ++i) {
        int idx = tid + 256 * i;
        int row = idx >> 2, cg = idx & 3;
        int g = (cg - (row >> 1)) & 3;       // inverse rotation on global src
        aptr[i] = A  + (size_t)row * N_HID + k0 + g * 8;
        bptr[i] = BT + (size_t)(n0 + row) * N_HID + k0 + g * 8;
        loff[i] = idx * 8;
    }

    f32x4 acc[4][4] = {};

    // prologue: stage kt=0 into buffer 0
    #pragma unroll
    for (int i = 0; i < 2; ++i) {
        gload_lds16(aptr[i], &As[0][loff[i]]);
        gload_lds16(bptr[i], &Bs[0][loff[i]]);
    }
    __syncthreads();

    int cur = 0;
    const int NT = (N_HID / KSPLIT) / 32;                  // 16 iters
    for (int kt = 0; kt < NT; ++kt) {
        if (kt + 1 < NT) {
            int kk = (kt + 1) * 32;
            int nxt = cur ^ 1;
            #pragma unroll
            for (int i = 0; i < 2; ++i) {
                gload_lds16(aptr[i] + kk, &As[nxt][loff[i]]);
                gload_lds16(bptr[i] + kk, &Bs[nxt][loff[i]]);
            }
        }
        const unsigned short* ca = As[cur];
        const unsigned short* cb = Bs[cur];
        sh8 af[4], bf[4];
        #pragma unroll
        for (int mt = 0; mt < 4; ++mt) {
            int row = wm + mt * 16 + l16;
            int c = (quad + (row >> 1)) & 3;
            af[mt] = *(const sh8*)&ca[row * 32 + c * 8];
        }
        #pragma unroll
        for (int nt2 = 0; nt2 < 4; ++nt2) {
            int row = wn + nt2 * 16 + l16;
            int c = (quad + (row >> 1)) & 3;
            bf[nt2] = *(const sh8*)&cb[row * 32 + c * 8];
        }
        #pragma unroll
        for (int mt = 0; mt < 4; ++mt)
            #pragma unroll
            for (int nt2 = 0; nt2 < 4; ++nt2)
                acc[mt][nt2] = __builtin_amdgcn_mfma_f32_16x16x32_bf16(
                    af[mt], bf[nt2], acc[mt][nt2], 0, 0, 0);
        __syncthreads();
        cur ^= 1;
    }

    float* pout = part + (size_t)ks * 128 * Nfull;
    #pragma unroll
    for (int mt = 0; mt < 4; ++mt)
        #pragma unroll
        for (int nt2 = 0; nt2 < 4; ++nt2) {
            int col = n0 + wn + nt2 * 16 + l16;
            #pragma unroll
            for (int r = 0; r < 4; ++r) {
                int m = wm + mt * 16 + quad * 4 + r;
                pout[(size_t)m * Nfull + col] = acc[mt][nt2][r];
            }
        }
}

// ---------------------------------------------------------------------------
// Merged per-step spk GEMMs: one dispatch computes BOTH the rec partials
// (blocks 0..255: 32 n-tiles x 8 ksplit) and the out partials (blocks
// 256..319: 8 n-tiles x 8 ksplit). When do_rec==0 (last dense step), grid=64
// and all blocks do out tiles. No grid-wide sync anywhere (round-7 lesson).
// ---------------------------------------------------------------------------
__global__ __launch_bounds__(256)
void spk_gemm_merged_kernel(const unsigned short* __restrict__ spk,
                            const unsigned short* __restrict__ WrecT,
                            const unsigned short* __restrict__ WoutT,
                            float* __restrict__ rec_part,
                            float* __restrict__ out_part,
                            int do_rec) {
    __shared__ __attribute__((aligned(16))) unsigned short As[2][128 * 32];
    __shared__ __attribute__((aligned(16))) unsigned short Bs[2][128 * 32];
    const int bid = blockIdx.x;
    const int tid = threadIdx.x;
    if (do_rec) {
        if (bid < 256)
            spk_tile_gemm(spk, WrecT, rec_part, N_HID, bid & 31, bid >> 5, As, Bs, tid);
        else {
            int o = bid - 256;
            spk_tile_gemm(spk, WoutT, out_part, N_OUT, o & 7, o >> 3, As, Bs, tid);
        }
    } else {
        spk_tile_gemm(spk, WoutT, out_part, N_OUT, bid & 7, bid >> 3, As, Bs, tid);
    }
}

// ---------------------------------------------------------------------------
// Transient pointwise step. grid = 512 (4 blocks per batch, quarter each),
// 256 threads. Thread (q,tid) owns t4 = q*256+tid: h cols 4*t4..4*t4+3 and
// o col t4 — elementwise identical math to the round-6 1024-thread version.
// ---------------------------------------------------------------------------
__global__ __launch_bounds__(256)
void transient_update_kernel(const float* __restrict__ inp,      // [B][Tc][N_HID]
                             const float* __restrict__ rec_part, // [KSPLIT][B][N_HID]
                             const float* __restrict__ out_part, // [KSPLIT][B][N_OUT]
                             float* __restrict__ h_mem,
                             float* __restrict__ o_mem,
                             unsigned short* __restrict__ spk,   // [B][N_HID] bf16
                             unsigned long long* __restrict__ maskg,
                             float* __restrict__ out,
                             int t_glob, int Tc, int has_rec, int has_out) {
    __shared__ __attribute__((aligned(16))) unsigned char spkb[256];
    const int b = blockIdx.x >> 2;
    const int q = blockIdx.x & 3;
    const int tid = threadIdx.x;
    const int t4 = q * 256 + tid;

    if (has_out) {
        float s = 0.f;
        #pragma unroll
        for (int ks = 0; ks < KSPLIT; ++ks)
            s += out_part[(size_t)ks * B_SZ * N_OUT + (size_t)b * N_OUT + t4];
        float o = TAU * o_mem[(size_t)b * N_OUT + t4] + s;
        o_mem[(size_t)b * N_OUT + t4] = o;
        out[((size_t)b * T_SZ + (t_glob - 1)) * N_OUT + t4] = o;
    }

    float rec[4] = {0.f, 0.f, 0.f, 0.f};
    if (has_rec) {
        #pragma unroll
        for (int ks = 0; ks < KSPLIT; ++ks) {
            float4 p = *(const float4*)(rec_part + (size_t)ks * B_SZ * N_HID
                                        + (size_t)b * N_HID + 4 * t4);
            rec[0] += p.x; rec[1] += p.y; rec[2] += p.z; rec[3] += p.w;
        }
    }

    unsigned short* sp = spk + (size_t)b * N_HID + 4 * t4;
    ush4 prev = *(const ush4*)sp;    // bf16 {0,1}; t_glob=0: h=0 so unused
    float4 iv = *(const float4*)(inp + ((size_t)b * Tc + t_glob) * N_HID + 4 * t4);
    float ivv[4] = {iv.x, iv.y, iv.z, iv.w};
    float* hp = h_mem + (size_t)b * N_HID + 4 * t4;
    float hv[4] = {hp[0], hp[1], hp[2], hp[3]};
    ush4 news;
    unsigned nib = 0;
    #pragma unroll
    for (int k = 0; k < 4; ++k) {
        float spf = bf2f(prev[k]);
        float v = TAU * hv[k] * (1.0f - spf) + (ivv[k] + REC_SCALE * rec[k]);
        hp[k] = v;
        bool s = (v >= THRESH);
        news[k] = s ? (unsigned short)0x3F80 : (unsigned short)0;
        nib |= (s ? 1u : 0u) << k;
    }
    *(ush4*)sp = news;
    spkb[tid] = (unsigned char)nib;
    __syncthreads();
    if (tid < 16) {
        uint4 qd = *(const uint4*)&spkb[tid * 16];
        unsigned w0 = pack4(qd.x) | (pack4(qd.y) << 16);
        unsigned w1 = pack4(qd.z) | (pack4(qd.w) << 16);
        maskg[b * 64 + q * 16 + tid] = (unsigned long long)w0
                                     | ((unsigned long long)w1 << 32);
    }
}

// ---------------------------------------------------------------------------
// min-side list build from a 64-bit word per lane (wave 0 only).
// ---------------------------------------------------------------------------
__device__ __forceinline__ void build_list_core(unsigned long long w,
                                                unsigned short* list,
                                                int* sh_n, int* sh_inact,
                                                int lane) {
    int tot = __builtin_popcountll(w);
    #pragma unroll
    for (int d = 32; d > 0; d >>= 1) tot += __shfl_xor(tot, d, 64);
    int inact = tot > (N_HID / 2);
    unsigned long long wsel = inact ? ~w : w;
    int c = __builtin_popcountll(wsel);
    int scan = c;
    #pragma unroll
    for (int d = 1; d < 64; d <<= 1) {
        int v = __shfl_up(scan, d, 64);
        if (lane >= d) scan += v;
    }
    int off = scan - c;
    while (wsel) {
        int bpos = __builtin_ctzll(wsel);
        list[off++] = (unsigned short)(lane * 64 + bpos);
        wsel &= wsel - 1;
    }
    if (lane == 0) {
        *sh_n = inact ? (N_HID - tot) : tot;
        *sh_inact = inact;
    }
}

// ---------------------------------------------------------------------------
// Sparse RSNN step loop for steps tloc0..tloc0+nsteps-1 of the current chunk.
// Round-5 restructure: the out-gather of step t and the rec-gather of step
// t+1 read the SAME spike list, so they are FUSED into one combined gather
// (per index j: Wo[j] 2B + Wb[j] 8B together). One latency-exposed gather
// phase per step instead of two, and the old "list readers done" barrier
// becomes redundant (the pre-build barrier orders gather-reads before the
// next build's list-writes) -> 2 barriers/step instead of 3.
// ---------------------------------------------------------------------------
__global__ __launch_bounds__(1024, 4)
void rsnn_step_kernel(const float* __restrict__ inp,            // [B][Tc][N_HID]
                      const unsigned short* __restrict__ WrecB, // [N_HID][N_HID] bf16
                      const unsigned short* __restrict__ WoutB, // [N_HID][N_OUT] bf16
                      const float* __restrict__ cs_rec,
                      const float* __restrict__ cs_out,
                      const float* __restrict__ out_part,       // [KSPLIT][B][N_OUT]
                      float* __restrict__ h_mem_g,
                      float* __restrict__ o_mem_g,
                      unsigned long long* __restrict__ mask_g,
                      float* __restrict__ out,
                      int t0, int Tc, int tloc0, int nsteps, int do_accum) {
    __shared__ unsigned long long mask[64];
    __shared__ __attribute__((aligned(16))) unsigned short list[N_HID];
    __shared__ __attribute__((aligned(16))) unsigned char spk[1024];
    __shared__ int sh_n;
    __shared__ int sh_inact;

    const int b = blockIdx.x;
    const int t = threadIdx.x;           // 0..1023
    const int lane = t & 63;
    const int wave = t >> 6;

    float hm[4], csr[4];
    #pragma unroll
    for (int k = 0; k < 4; ++k) {
        hm[k]  = h_mem_g[(size_t)b * N_HID + 4 * t + k];
        csr[k] = cs_rec[4 * t + k];
    }
    float om  = o_mem_g[(size_t)b * N_OUT + t];
    float cso = cs_out[t];
    if (do_accum) {
        float s = 0.f;
        #pragma unroll
        for (int ks = 0; ks < KSPLIT; ++ks)
            s += out_part[(size_t)ks * B_SZ * N_OUT + (size_t)b * N_OUT + t];
        om = TAU * om + s;
        out[((size_t)b * T_SZ + (t0 + tloc0 - 1)) * N_OUT + t] = om;
    }
    if (t < 64) mask[t] = mask_g[b * 64 + t];
    __syncthreads();

    // previous-step spike flags for cols 4t..4t+3 (hard reset term)
    float spf[4];
    {
        unsigned long long w = mask[t >> 4];
        int sh = 4 * (t & 15);
        #pragma unroll
        for (int k = 0; k < 4; ++k)
            spf[k] = (float)((w >> (sh + k)) & 1ULL);
    }
    if (wave == 0) build_list_core(mask[lane], list, &sh_n, &sh_inact, lane);
    __syncthreads();

    const unsigned short* Wb = WrecB + 4 * t;
    const unsigned short* Wo = WoutB + t;

    // ---- prologue: rec gather for the FIRST step from the initial list ----
    float rec_cur[4];
    {
        int n = sh_n, inact = sh_inact;
        float a[8][4] = {};
        int i = 0;
        for (; i + 8 <= n; i += 8) {
            ush8 jv = *(const ush8*)&list[i];
            #pragma unroll
            for (int r = 0; r < 8; ++r) {
                uint2 v = *(const uint2*)(Wb + (size_t)jv[r] * N_HID);
                a[r][0] += __uint_as_float(v.x << 16);
                a[r][1] += __uint_as_float(v.x & 0xFFFF0000u);
                a[r][2] += __uint_as_float(v.y << 16);
                a[r][3] += __uint_as_float(v.y & 0xFFFF0000u);
            }
        }
        for (; i < n; ++i) {
            uint2 v = *(const uint2*)(Wb + (size_t)list[i] * N_HID);
            a[0][0] += __uint_as_float(v.x << 16);
            a[0][1] += __uint_as_float(v.x & 0xFFFF0000u);
            a[0][2] += __uint_as_float(v.y << 16);
            a[0][3] += __uint_as_float(v.y & 0xFFFF0000u);
        }
        #pragma unroll
        for (int k = 0; k < 4; ++k) {
            float racc = ((a[0][k] + a[1][k]) + (a[2][k] + a[3][k]))
                       + ((a[4][k] + a[5][k]) + (a[6][k] + a[7][k]));
            rec_cur[k] = REC_SCALE * (inact ? (csr[k] - racc) : racc);
        }
    }

    // prefetched input (double-buffered so HBM latency hides under the step)
    float4 ivq = *(const float4*)(inp + ((size_t)b * Tc + tloc0) * N_HID + 4 * t);

    for (int tl = 0; tl < nsteps; ++tl) {
        float4 iv_next = make_float4(0.f, 0.f, 0.f, 0.f);
        bool more = (tl + 1 < nsteps);
        if (more)
            iv_next = *(const float4*)(inp + ((size_t)b * Tc + tloc0 + tl + 1) * N_HID
                                       + 4 * t);

        // ---- membrane update + spike decision (rec_cur precomputed) ----
        float ivv[4] = {ivq.x, ivq.y, ivq.z, ivq.w};
        unsigned nib = 0;
        #pragma unroll
        for (int k = 0; k < 4; ++k) {
            float v = TAU * hm[k] * (1.0f - spf[k]) + (ivv[k] + rec_cur[k]);
            hm[k] = v;
            bool s = (v >= THRESH);
            spf[k] = s ? 1.0f : 0.0f;
            nib |= (s ? 1u : 0u) << k;
        }
        spk[t] = (unsigned char)nib;   // prev wave-0 spk read was pre-B3(t-1)
        __syncthreads();   // B2: spk visible; orders prev gather's list reads
                           //     before this build's list writes
        if (wave == 0) {
            uint4 q = *(const uint4*)&spk[lane * 16];
            unsigned w0 = pack4(q.x) | (pack4(q.y) << 16);
            unsigned w1 = pack4(q.z) | (pack4(q.w) << 16);
            unsigned long long w = (unsigned long long)w0
                                 | ((unsigned long long)w1 << 32);
            mask[lane] = w;
            build_list_core(w, list, &sh_n, &sh_inact, lane);
        }
        __syncthreads();   // B3: list/counts ready

        // ---- FUSED gather over min side of NEW spikes:
        //      out contribution (this step) + rec input (next step) ----
        int n2 = sh_n, inact = sh_inact;
        float a[4][4] = {};
        float o4[4] = {0.f, 0.f, 0.f, 0.f};
        int i = 0;
        for (; i + 4 <= n2; i += 4) {
            ush4 jv = *(const ush4*)&list[i];
            #pragma unroll
            for (int r = 0; r < 4; ++r) {
                uint2 v = *(const uint2*)(Wb + (size_t)jv[r] * N_HID);
                o4[r] += bf2f(Wo[(size_t)jv[r] * N_OUT]);
                a[r][0] += __uint_as_float(v.x << 16);
                a[r][1] += __uint_as_float(v.x & 0xFFFF0000u);
                a[r][2] += __uint_as_float(v.y << 16);
                a[r][3] += __uint_as_float(v.y & 0xFFFF0000u);
            }
        }
        for (; i < n2; ++i) {
            int j = list[i];
            uint2 v = *(const uint2*)(Wb + (size_t)j * N_HID);
            o4[0] += bf2f(Wo[(size_t)j * N_OUT]);
            a[0][0] += __uint_as_float(v.x << 16);
            a[0][1] += __uint_as_float(v.x & 0xFFFF0000u);
            a[0][2] += __uint_as_float(v.y << 16);
            a[0][3] += __uint_as_float(v.y & 0xFFFF0000u);
        }
        float oacc = (o4[0] + o4[1]) + (o4[2] + o4[3]);
        om = TAU * om + (inact ? (cso - oacc) : oacc);
        out[((size_t)b * T_SZ + (t0 + tloc0 + tl)) * N_OUT + t] = om;
        #pragma unroll
        for (int k = 0; k < 4; ++k) {
            float racc = (a[0][k] + a[1][k]) + (a[2][k] + a[3][k]);
            rec_cur[k] = REC_SCALE * (inact ? (csr[k] - racc) : racc);
        }

        if (more) ivq = iv_next;
    }

    #pragma unroll
    for (int k = 0; k < 4; ++k)
        h_mem_g[(size_t)b * N_HID + 4 * t + k] = hm[k];
    o_mem_g[(size_t)b * N_OUT + t] = om;
    __syncthreads();
    if (t < 64) mask_g[b * 64 + t] = mask[t];
}

// ---------------------------------------------------------------------------
extern "C" void kernel_launch(void* const* d_in, const int* in_sizes, int n_in,
                              void* d_out, int out_size, void* d_ws, size_t ws_size,
                              hipStream_t stream) {
    const float* x    = (const float*)d_in[0];
    const float* Wfc1 = (const float*)d_in[1];
    const float* Wrec = (const float*)d_in[2];
    const float* Wout = (const float*)d_in[3];
    float* out = (float*)d_out;

    // workspace layout (all 16B-aligned)
    float* h_mem = (float*)d_ws;                               // 2 MB
    float* o_mem = h_mem + B_SZ * N_HID;                       // 0.5 MB
    unsigned long long* maskg =
        (unsigned long long*)(o_mem + B_SZ * N_OUT);           // 64 KB
    float* cs_rec = (float*)(maskg + B_SZ * 64);               // 16 KB
    float* cs_out = cs_rec + N_HID;                            // 4 KB
    unsigned short* WrecB = (unsigned short*)(cs_out + N_OUT); // 33.55 MB
    unsigned short* WoutB = WrecB + (size_t)N_HID * N_HID;     // 8.39 MB
    unsigned short* WrecT = WoutB + (size_t)N_HID * N_OUT;     // 33.55 MB
    unsigned short* WoutT = WrecT + (size_t)N_HID * N_HID;     // 8.39 MB
    char* Bt = (char*)(WoutT + (size_t)N_OUT * N_HID);         // 8.39 MB (i8)
    unsigned short* spk = (unsigned short*)(Bt + (size_t)N_HID * 2048); // 1.05 MB
    float* rec_part = (float*)(spk + (size_t)B_SZ * N_HID);    // 16.78 MB
    float* out_part = rec_part + (size_t)KSPLIT * B_SZ * N_HID;// 4.19 MB
    char* Ax = (char*)(out_part + (size_t)KSPLIT * B_SZ * N_OUT);
    // inp_chunk follows Ax (Tc-dependent)

    size_t fixed_bytes = (size_t)(B_SZ * N_HID + B_SZ * N_OUT) * 4
                       + (size_t)B_SZ * 64 * 8
                       + (size_t)(N_HID + N_OUT) * 4
                       + 2 * (size_t)N_HID * N_HID * 2          // WrecB + WrecT
                       + 2 * (size_t)N_HID * N_OUT * 2          // WoutB + WoutT
                       + (size_t)N_HID * 2048                   // Bt (int8)
                       + (size_t)B_SZ * N_HID * 2               // spk
                       + (size_t)KSPLIT * B_SZ * (N_HID + N_OUT) * 4;
    int Tc = 64;
    while (Tc > 8 &&
           fixed_bytes + (size_t)Tc * (B_SZ * 2048 + B_SZ * N_HID * 4) > ws_size)
        Tc >>= 1;
    float* inp_chunk = (float*)(Ax + (size_t)B_SZ * Tc * 2048);

    int state_floats = B_SZ * N_HID + B_SZ * N_OUT + B_SZ * 64 * 2;
    zero_state_kernel<<<256, 256, 0, stream>>>(h_mem, state_floats);
    // fused bf16 copy + transpose (one read of each weight matrix)
    convT_bf16_kernel<<<dim3(N_HID / 64, N_HID / 64), 256, 0, stream>>>(
        Wrec, WrecB, WrecT, N_HID, N_HID);
    convT_bf16_kernel<<<dim3(N_OUT / 64, N_HID / 64), 256, 0, stream>>>(
        Wout, WoutB, WoutT, N_HID, N_OUT);
    colsum_bf16_kernel<<<80, 256, 0, stream>>>(WrecB, WoutB, cs_rec, cs_out);
    convert_w_kernel<<<dim3(32, 64), 256, 0, stream>>>(Wfc1, Bt);

    for (int t0 = 0; t0 < T_SZ; t0 += Tc) {
        convert_x_kernel<<<2048, 256, 0, stream>>>(x, Ax, t0, Tc);
        int my = (B_SZ * Tc) / 128;   // multiple of 8 for Tc >= 8
        fc1_mfma_kernel<<<32 * my, 256, 0, stream>>>(Ax, Bt, inp_chunk, my);

        if (t0 == 0) {
            // dense transient: steps 0..S_DENSE-1, two dispatches per step
            for (int tg = 0; tg < S_DENSE; ++tg) {
                transient_update_kernel<<<B_SZ * 4, 256, 0, stream>>>(
                    inp_chunk, rec_part, out_part, h_mem, o_mem, spk, maskg, out,
                    tg, Tc, /*has_rec=*/tg > 0, /*has_out=*/tg > 0);
                int do_rec = (tg + 1 < S_DENSE);
                spk_gemm_merged_kernel<<<do_rec ? 320 : 64, 256, 0, stream>>>(
                    spk, WrecT, WoutT, rec_part, out_part, do_rec);
            }
            rsnn_step_kernel<<<B_SZ, 1024, 0, stream>>>(
                inp_chunk, WrecB, WoutB, cs_rec, cs_out, out_part,
                h_mem, o_mem, maskg, out,
                t0, Tc, /*tloc0=*/S_DENSE, /*nsteps=*/Tc - S_DENSE, /*do_accum=*/1);
        } else {
            rsnn_step_kernel<<<B_SZ, 1024, 0, stream>>>(
                inp_chunk, WrecB, WoutB, cs_rec, cs_out, out_part,
                h_mem, o_mem, maskg, out,
                t0, Tc, /*tloc0=*/0, /*nsteps=*/Tc, /*do_accum=*/0);
        }
    }
}

// Round 6
// 577.296 us; speedup vs baseline: 1.0004x; 1.0004x over previous
//
#include <hip/hip_runtime.h>
#include <stdint.h>

#define B_SZ 128
#define T_SZ 64
#define N_IN 1024
#define N_HID 4096
#define N_OUT 1024
#define TAU 0.9f
#define THRESH 0.5f
#define REC_SCALE 0.1f
#define S_DENSE 5          // steps 0..4 computed via dense MFMA GEMMs
#define KSPLIT 8           // K-split for spk GEMMs (4096/8 = 512 per chunk)

typedef __attribute__((ext_vector_type(8))) short sh8;
typedef __attribute__((ext_vector_type(4))) float f32x4;
typedef __attribute__((ext_vector_type(4))) int i32x4;
typedef __attribute__((ext_vector_type(4))) unsigned short ush4;
typedef __attribute__((ext_vector_type(8))) unsigned short ush8;

// ---------------------------------------------------------------------------
// helpers
// ---------------------------------------------------------------------------
__device__ __forceinline__ unsigned short f2bf_rn(float f) {
    unsigned u = __float_as_uint(f);
    unsigned r = (u + 0x7FFFu + ((u >> 16) & 1u)) >> 16;
    return (unsigned short)r;
}
__device__ __forceinline__ float bf2f(unsigned short h) {
    return __uint_as_float((unsigned)h << 16);
}
__device__ __forceinline__ void gload_lds16(const void* g, void* l) {
    __builtin_amdgcn_global_load_lds(
        (const __attribute__((address_space(1))) void*)g,
        (__attribute__((address_space(3))) void*)l, 16, 0, 0);
}
// compress low nibbles of 4 bytes into 16 bits
__device__ __forceinline__ unsigned pack4(unsigned a) {
    a &= 0x0F0F0F0Fu;
    a = (a | (a >> 4)) & 0x00FF00FFu;
    a = (a | (a >> 8)) & 0x0000FFFFu;
    return a;
}

// ---------------------------------------------------------------------------
__global__ void zero_state_kernel(float* p, int n) {
    int i = blockIdx.x * blockDim.x + threadIdx.x;
    int stride = gridDim.x * blockDim.x;
    for (; i < n; i += stride) p[i] = 0.0f;
}

// ---------------------------------------------------------------------------
// fused: W [R][C] fp32 -> WB [R][C] bf16 AND WT [C][R] bf16 (one read of W)
// ---------------------------------------------------------------------------
__global__ __launch_bounds__(256)
void convT_bf16_kernel(const float* __restrict__ W,
                       unsigned short* __restrict__ WB,
                       unsigned short* __restrict__ WT, int R, int C) {
    __shared__ float ts[64][65];
    int tid = threadIdx.x;
    int c0 = blockIdx.x * 64;
    int r0 = blockIdx.y * 64;
    #pragma unroll
    for (int rr = 0; rr < 16; ++rr) {
        int r = rr * 4 + (tid >> 6);
        int c = tid & 63;
        float v = W[(size_t)(r0 + r) * C + c0 + c];
        ts[r][c] = v;
        WB[(size_t)(r0 + r) * C + c0 + c] = f2bf_rn(v);
    }
    __syncthreads();
    #pragma unroll
    for (int rr = 0; rr < 16; ++rr) {
        int c = rr * 4 + (tid >> 6);
        int r = tid & 63;
        WT[(size_t)(c0 + c) * R + r0 + r] = f2bf_rn(ts[r][c]);
    }
}

// ---------------------------------------------------------------------------
// column sums of the bf16-rounded W_rec / W_out (for the sparse complement)
// ---------------------------------------------------------------------------
__global__ __launch_bounds__(256)
void colsum_bf16_kernel(const unsigned short* __restrict__ WrecB,
                        const unsigned short* __restrict__ WoutB,
                        float* __restrict__ cs_rec, float* __restrict__ cs_out) {
    __shared__ float part[4][64];
    int tid = threadIdx.x;
    int c = tid & 63, q = tid >> 6;
    int col = blockIdx.x * 64 + c;  // 0..5119
    float s = 0.f;
    if (col < N_HID) {
        const unsigned short* p = WrecB + col + (size_t)q * 1024 * N_HID;
        for (int j = 0; j < 1024; ++j) s += bf2f(p[(size_t)j * N_HID]);
    } else {
        int o = col - N_HID;
        const unsigned short* p = WoutB + o + (size_t)q * 1024 * N_OUT;
        for (int j = 0; j < 1024; ++j) s += bf2f(p[(size_t)j * N_OUT]);
    }
    part[q][c] = s;
    __syncthreads();
    if (tid < 64) {
        float tot = part[0][tid] + part[1][tid] + part[2][tid] + part[3][tid];
        int col2 = blockIdx.x * 64 + tid;
        if (col2 < N_HID) cs_rec[col2] = tot;
        else              cs_out[col2 - N_HID] = tot;
    }
}

// ---------------------------------------------------------------------------
// x [B,T,1024] fp32 -> Ax [128*Tc][2048] int8 limbs: cols 0..1023 = X1 (high
// 6 bits), 1024..2047 = X0 (low 7 bits); x ~= 2^-13 * (X1*128 + X0).
// ---------------------------------------------------------------------------
__global__ __launch_bounds__(256)
void convert_x_kernel(const float* __restrict__ x, char* __restrict__ Ax,
                      int t0, int Tc) {
    int total4 = B_SZ * Tc * (N_IN / 4);
    int i = blockIdx.x * blockDim.x + threadIdx.x;
    int stride = gridDim.x * blockDim.x;
    for (; i < total4; i += stride) {
        int m = i >> 8;
        int c4 = i & 255;
        int b = m / Tc, tl = m - b * Tc;
        float4 v = *(const float4*)(x + ((size_t)(b * T_SZ + t0 + tl) * N_IN) + c4 * 4);
        float f[4] = {v.x, v.y, v.z, v.w};
        char hi[4], lo[4];
        #pragma unroll
        for (int j = 0; j < 4; ++j) {
            int X = (int)rintf(f[j] * 8192.0f);
            X = X < 0 ? 0 : (X > 8191 ? 8191 : X);
            hi[j] = (char)(X >> 7);          // 0..63
            lo[j] = (char)(X & 127);         // 0..127
        }
        char* row = Ax + (size_t)m * 2048;
        *(char4*)(row + c4 * 4)        = *(const char4*)hi;
        *(char4*)(row + 1024 + c4 * 4) = *(const char4*)lo;
    }
}

// ---------------------------------------------------------------------------
// W_fc1 [1024][4096] fp32 -> Bt [4096][2048] int8 limbs, transposed:
// cols 0..1023 = V1, 1024..2047 = V0; W ~= 2^-19 * (V1*128 + V0).
// ---------------------------------------------------------------------------
__global__ __launch_bounds__(256)
void convert_w_kernel(const float* __restrict__ W, char* __restrict__ Bt) {
    __shared__ float ts[32][65];
    int tid = threadIdx.x;
    int k0 = blockIdx.x * 32;
    int n0 = blockIdx.y * 64;
    #pragma unroll
    for (int rr = 0; rr < 8; ++rr) {
        int kl = (tid >> 6) * 8 + rr;
        int nl = tid & 63;
        ts[kl][nl] = W[(size_t)(k0 + kl) * N_HID + n0 + nl];
    }
    __syncthreads();
    #pragma unroll
    for (int rr = 0; rr < 8; ++rr) {
        int nl = (tid >> 5) + rr * 8;
        int kl = tid & 31;
        float v = ts[kl][nl];
        int V = (int)rintf(v * 524288.0f);
        V = V < -16383 ? -16383 : (V > 16383 ? 16383 : V);
        char* row = Bt + (size_t)(n0 + nl) * 2048;
        row[k0 + kl]        = (char)(V >> 7);   // -128..127
        row[1024 + k0 + kl] = (char)(V & 127);  // 0..127
    }
}

// ---------------------------------------------------------------------------
// fc1 GEMM via int8 MFMA, virtual K = 3072 (X0*V0 dropped, sigma~2e-5):
//   segment 1 (16 iters): X1 * V1   -> acc <<= 7
//   segment 2 (32 iters): [X1|X0] * [V0|V1] cross terms
//   C = 2^-25 * (float)acc
// Round-6 VALU fix: round-5 counters showed VALUBusy 80% / MfmaUtil 31% —
// the rotation addressing recomputed 8 fragment addresses + buffer select +
// branchy ak/bk EVERY iteration (~100 VALU ops/thread/iter, all invariant).
// Now: fragment LDS byte-offsets hoisted (computed once), loop split into two
// branch-free segments, unrolled x2 so the double-buffer index is a literal,
// boundary iterations peeled. Same math/sync -> bitwise-identical output.
// ---------------------------------------------------------------------------
__global__ __launch_bounds__(256)
void fc1_mfma_kernel(const char* __restrict__ A,
                     const char* __restrict__ Bt,
                     float* __restrict__ C, int my) {
    __shared__ __attribute__((aligned(16))) char As[2][128 * 64];
    __shared__ __attribute__((aligned(16))) char Bs[2][128 * 64];
    const int tid = threadIdx.x;
    const int lane = tid & 63;
    const int wave = tid >> 6;
    const int wm = (wave >> 1) * 64;   // waves 2(M) x 2(N)
    const int wn = (wave & 1) * 64;
    const int quad = lane >> 4, l16 = lane & 15;

    // XCD swizzle: XCD k owns m-tiles [k*my/8, (k+1)*my/8), n varies outer.
    const int lin = blockIdx.x;
    const int ych = my >> 3;                 // my % 8 == 0 guaranteed
    const int xcd = lin & 7, rel = lin >> 3;
    const int m0 = (xcd * ych + (rel % ych)) * 128;
    const int n0 = (rel / ych) * 128;

    const char* aptr[2];
    const char* bptr[2];
    int loff[2];
    #pragma unroll
    for (int i = 0; i < 2; ++i) {
        int idx = i * 256 + tid;             // 0..511 -> row=idx>>2, ch=idx&3
        int row = idx >> 2, ch = idx & 3;
        int g = (ch - (row >> 1)) & 3;       // inverse rotation on global src
        aptr[i] = A  + (size_t)(m0 + row) * 2048 + g * 16;
        bptr[i] = Bt + (size_t)(n0 + row) * 2048 + g * 16;
        loff[i] = idx * 16;                  // linear LDS dest (DMA constraint)
    }

    // loop-invariant fragment LDS byte offsets (rotated chunk addressing)
    int offA[4], offB[4];
    #pragma unroll
    for (int mt = 0; mt < 4; ++mt) {
        int ra = wm + mt * 16 + l16;
        offA[mt] = ra * 64 + (((quad + (ra >> 1)) & 3) << 4);
        int rb = wn + mt * 16 + l16;
        offB[mt] = rb * 64 + (((quad + (rb >> 1)) & 3) << 4);
    }

    i32x4 acc[4][4] = {};

    auto stage = [&](int buf, int ak, int bk) {
        gload_lds16(aptr[0] + ak, &As[buf][loff[0]]);
        gload_lds16(aptr[1] + ak, &As[buf][loff[1]]);
        gload_lds16(bptr[0] + bk, &Bs[buf][loff[0]]);
        gload_lds16(bptr[1] + bk, &Bs[buf][loff[1]]);
    };
    auto compute = [&](int buf) {
        const char* ca = As[buf];
        const char* cb = Bs[buf];
        i32x4 af[4], bf[4];
        #pragma unroll
        for (int mt = 0; mt < 4; ++mt) af[mt] = *(const i32x4*)(ca + offA[mt]);
        #pragma unroll
        for (int nt = 0; nt < 4; ++nt) bf[nt] = *(const i32x4*)(cb + offB[nt]);
        #pragma unroll
        for (int mt = 0; mt < 4; ++mt)
            #pragma unroll
            for (int nt = 0; nt < 4; ++nt)
                acc[mt][nt] = __builtin_amdgcn_mfma_i32_16x16x64_i8(
                    af[mt], bf[nt], acc[mt][nt], 0, 0, 0);
    };

    // ---- segment 1: X1 * V1 (16 iters, branch-free body) ----
    stage(0, 0, 0);
    __syncthreads();
    #pragma unroll 2
    for (int kt = 0; kt < 15; ++kt) {
        int k = (kt + 1) * 64;
        stage((kt + 1) & 1, k, k);
        compute(kt & 1);
        __syncthreads();
    }
    stage(0, 0, 1024);                  // first seg-2 tile into buf 0
    compute(1);                          // kt = 15
    __syncthreads();

    // ---- scale hi-limb partial by 128 (exact) ----
    #pragma unroll
    for (int mt = 0; mt < 4; ++mt)
        #pragma unroll
        for (int nt = 0; nt < 4; ++nt)
            #pragma unroll
            for (int r = 0; r < 4; ++r)
                acc[mt][nt][r] <<= 7;

    // ---- segment 2: cross terms over concatenated K=2048 (32 iters) ----
    #pragma unroll 2
    for (int kt = 0; kt < 31; ++kt) {
        int a = (kt + 1) * 64;
        stage((kt + 1) & 1, a, (a + 1024) & 2047);
        compute(kt & 1);
        __syncthreads();
    }
    compute(1);                          // kt = 31

    #pragma unroll
    for (int mt = 0; mt < 4; ++mt)
        #pragma unroll
        for (int nt = 0; nt < 4; ++nt) {
            int col = n0 + wn + nt * 16 + l16;
            #pragma unroll
            for (int r = 0; r < 4; ++r) {
                int m = m0 + wm + mt * 16 + quad * 4 + r;
                C[(size_t)m * N_HID + col] = 0x1p-25f * (float)acc[mt][nt][r];
            }
        }
}

// ---------------------------------------------------------------------------
// One 128x128 C-tile of part[ks][128][Nfull] = spk[128][4096] @ BT[...]^T over
// a 512-wide K chunk. Same VALU treatment: hoisted fragment offsets,
// branch-free unrolled loop with literal buffer indices.
// ---------------------------------------------------------------------------
__device__ __forceinline__ void spk_tile_gemm(const unsigned short* __restrict__ A,
                                              const unsigned short* __restrict__ BT,
                                              float* __restrict__ part, int Nfull,
                                              int nt, int ks,
                                              unsigned short (*As)[128 * 32],
                                              unsigned short (*Bs)[128 * 32],
                                              int tid) {
    const int lane = tid & 63;
    const int wave = tid >> 6;
    const int wm = (wave >> 1) * 64;
    const int wn = (wave & 1) * 64;
    const int quad = lane >> 4, l16 = lane & 15;
    const int n0 = nt * 128;
    const int k0 = ks * (N_HID / KSPLIT);

    const unsigned short* aptr[2];
    const unsigned short* bptr[2];
    int loff[2];
    #pragma unroll
    for (int i = 0; i < 2; ++i) {
        int idx = tid + 256 * i;
        int row = idx >> 2, cg = idx & 3;
        int g = (cg - (row >> 1)) & 3;       // inverse rotation on global src
        aptr[i] = A  + (size_t)row * N_HID + k0 + g * 8;
        bptr[i] = BT + (size_t)(n0 + row) * N_HID + k0 + g * 8;
        loff[i] = idx * 8;
    }

    // loop-invariant fragment LDS offsets (in shorts)
    int offA[4], offB[4];
    #pragma unroll
    for (int mt = 0; mt < 4; ++mt) {
        int ra = wm + mt * 16 + l16;
        offA[mt] = ra * 32 + (((quad + (ra >> 1)) & 3) << 3);
        int rb = wn + mt * 16 + l16;
        offB[mt] = rb * 32 + (((quad + (rb >> 1)) & 3) << 3);
    }

    f32x4 acc[4][4] = {};

    auto stage = [&](int buf, int kk) {
        gload_lds16(aptr[0] + kk, &As[buf][loff[0]]);
        gload_lds16(aptr[1] + kk, &As[buf][loff[1]]);
        gload_lds16(bptr[0] + kk, &Bs[buf][loff[0]]);
        gload_lds16(bptr[1] + kk, &Bs[buf][loff[1]]);
    };
    auto compute = [&](int buf) {
        const unsigned short* ca = As[buf];
        const unsigned short* cb = Bs[buf];
        sh8 af[4], bf[4];
        #pragma unroll
        for (int mt = 0; mt < 4; ++mt) af[mt] = *(const sh8*)(ca + offA[mt]);
        #pragma unroll
        for (int nt2 = 0; nt2 < 4; ++nt2) bf[nt2] = *(const sh8*)(cb + offB[nt2]);
        #pragma unroll
        for (int mt = 0; mt < 4; ++mt)
            #pragma unroll
            for (int nt2 = 0; nt2 < 4; ++nt2)
                acc[mt][nt2] = __builtin_amdgcn_mfma_f32_16x16x32_bf16(
                    af[mt], bf[nt2], acc[mt][nt2], 0, 0, 0);
    };

    stage(0, 0);
    __syncthreads();
    #pragma unroll 2
    for (int kt = 0; kt < 15; ++kt) {            // 16 K-tiles total
        stage((kt + 1) & 1, (kt + 1) * 32);
        compute(kt & 1);
        __syncthreads();
    }
    compute(1);                                   // kt = 15

    float* pout = part + (size_t)ks * 128 * Nfull;
    #pragma unroll
    for (int mt = 0; mt < 4; ++mt)
        #pragma unroll
        for (int nt2 = 0; nt2 < 4; ++nt2) {
            int col = n0 + wn + nt2 * 16 + l16;
            #pragma unroll
            for (int r = 0; r < 4; ++r) {
                int m = wm + mt * 16 + quad * 4 + r;
                pout[(size_t)m * Nfull + col] = acc[mt][nt2][r];
            }
        }
}

// ---------------------------------------------------------------------------
// Merged per-step spk GEMMs: one dispatch computes BOTH the rec partials
// (blocks 0..255: 32 n-tiles x 8 ksplit) and the out partials (blocks
// 256..319: 8 n-tiles x 8 ksplit). When do_rec==0 (last dense step), grid=64
// and all blocks do out tiles. No grid-wide sync anywhere (round-7 lesson).
// ---------------------------------------------------------------------------
__global__ __launch_bounds__(256)
void spk_gemm_merged_kernel(const unsigned short* __restrict__ spk,
                            const unsigned short* __restrict__ WrecT,
                            const unsigned short* __restrict__ WoutT,
                            float* __restrict__ rec_part,
                            float* __restrict__ out_part,
                            int do_rec) {
    __shared__ __attribute__((aligned(16))) unsigned short As[2][128 * 32];
    __shared__ __attribute__((aligned(16))) unsigned short Bs[2][128 * 32];
    const int bid = blockIdx.x;
    const int tid = threadIdx.x;
    if (do_rec) {
        if (bid < 256)
            spk_tile_gemm(spk, WrecT, rec_part, N_HID, bid & 31, bid >> 5, As, Bs, tid);
        else {
            int o = bid - 256;
            spk_tile_gemm(spk, WoutT, out_part, N_OUT, o & 7, o >> 3, As, Bs, tid);
        }
    } else {
        spk_tile_gemm(spk, WoutT, out_part, N_OUT, bid & 7, bid >> 3, As, Bs, tid);
    }
}

// ---------------------------------------------------------------------------
// Transient pointwise step. grid = 512 (4 blocks per batch, quarter each),
// 256 threads. Thread (q,tid) owns t4 = q*256+tid: h cols 4*t4..4*t4+3 and
// o col t4.
// ---------------------------------------------------------------------------
__global__ __launch_bounds__(256)
void transient_update_kernel(const float* __restrict__ inp,      // [B][Tc][N_HID]
                             const float* __restrict__ rec_part, // [KSPLIT][B][N_HID]
                             const float* __restrict__ out_part, // [KSPLIT][B][N_OUT]
                             float* __restrict__ h_mem,
                             float* __restrict__ o_mem,
                             unsigned short* __restrict__ spk,   // [B][N_HID] bf16
                             unsigned long long* __restrict__ maskg,
                             float* __restrict__ out,
                             int t_glob, int Tc, int has_rec, int has_out) {
    __shared__ __attribute__((aligned(16))) unsigned char spkb[256];
    const int b = blockIdx.x >> 2;
    const int q = blockIdx.x & 3;
    const int tid = threadIdx.x;
    const int t4 = q * 256 + tid;

    if (has_out) {
        float s = 0.f;
        #pragma unroll
        for (int ks = 0; ks < KSPLIT; ++ks)
            s += out_part[(size_t)ks * B_SZ * N_OUT + (size_t)b * N_OUT + t4];
        float o = TAU * o_mem[(size_t)b * N_OUT + t4] + s;
        o_mem[(size_t)b * N_OUT + t4] = o;
        out[((size_t)b * T_SZ + (t_glob - 1)) * N_OUT + t4] = o;
    }

    float rec[4] = {0.f, 0.f, 0.f, 0.f};
    if (has_rec) {
        #pragma unroll
        for (int ks = 0; ks < KSPLIT; ++ks) {
            float4 p = *(const float4*)(rec_part + (size_t)ks * B_SZ * N_HID
                                        + (size_t)b * N_HID + 4 * t4);
            rec[0] += p.x; rec[1] += p.y; rec[2] += p.z; rec[3] += p.w;
        }
    }

    unsigned short* sp = spk + (size_t)b * N_HID + 4 * t4;
    ush4 prev = *(const ush4*)sp;    // bf16 {0,1}; t_glob=0: h=0 so unused
    float4 iv = *(const float4*)(inp + ((size_t)b * Tc + t_glob) * N_HID + 4 * t4);
    float ivv[4] = {iv.x, iv.y, iv.z, iv.w};
    float* hp = h_mem + (size_t)b * N_HID + 4 * t4;
    float hv[4] = {hp[0], hp[1], hp[2], hp[3]};
    ush4 news;
    unsigned nib = 0;
    #pragma unroll
    for (int k = 0; k < 4; ++k) {
        float spf = bf2f(prev[k]);
        float v = TAU * hv[k] * (1.0f - spf) + (ivv[k] + REC_SCALE * rec[k]);
        hp[k] = v;
        bool s = (v >= THRESH);
        news[k] = s ? (unsigned short)0x3F80 : (unsigned short)0;
        nib |= (s ? 1u : 0u) << k;
    }
    *(ush4*)sp = news;
    spkb[tid] = (unsigned char)nib;
    __syncthreads();
    if (tid < 16) {
        uint4 qd = *(const uint4*)&spkb[tid * 16];
        unsigned w0 = pack4(qd.x) | (pack4(qd.y) << 16);
        unsigned w1 = pack4(qd.z) | (pack4(qd.w) << 16);
        maskg[b * 64 + q * 16 + tid] = (unsigned long long)w0
                                     | ((unsigned long long)w1 << 32);
    }
}

// ---------------------------------------------------------------------------
// min-side list build from a 64-bit word per lane (wave 0 only).
// ---------------------------------------------------------------------------
__device__ __forceinline__ void build_list_core(unsigned long long w,
                                                unsigned short* list,
                                                int* sh_n, int* sh_inact,
                                                int lane) {
    int tot = __builtin_popcountll(w);
    #pragma unroll
    for (int d = 32; d > 0; d >>= 1) tot += __shfl_xor(tot, d, 64);
    int inact = tot > (N_HID / 2);
    unsigned long long wsel = inact ? ~w : w;
    int c = __builtin_popcountll(wsel);
    int scan = c;
    #pragma unroll
    for (int d = 1; d < 64; d <<= 1) {
        int v = __shfl_up(scan, d, 64);
        if (lane >= d) scan += v;
    }
    int off = scan - c;
    while (wsel) {
        int bpos = __builtin_ctzll(wsel);
        list[off++] = (unsigned short)(lane * 64 + bpos);
        wsel &= wsel - 1;
    }
    if (lane == 0) {
        *sh_n = inact ? (N_HID - tot) : tot;
        *sh_inact = inact;
    }
}

// ---------------------------------------------------------------------------
// Sparse RSNN step loop for steps tloc0..tloc0+nsteps-1 of the current chunk.
// Fused gather (round 5): out contribution of step t and rec input of step
// t+1 read the same list; 2 barriers/step.
// ---------------------------------------------------------------------------
__global__ __launch_bounds__(1024, 4)
void rsnn_step_kernel(const float* __restrict__ inp,            // [B][Tc][N_HID]
                      const unsigned short* __restrict__ WrecB, // [N_HID][N_HID] bf16
                      const unsigned short* __restrict__ WoutB, // [N_HID][N_OUT] bf16
                      const float* __restrict__ cs_rec,
                      const float* __restrict__ cs_out,
                      const float* __restrict__ out_part,       // [KSPLIT][B][N_OUT]
                      float* __restrict__ h_mem_g,
                      float* __restrict__ o_mem_g,
                      unsigned long long* __restrict__ mask_g,
                      float* __restrict__ out,
                      int t0, int Tc, int tloc0, int nsteps, int do_accum) {
    __shared__ unsigned long long mask[64];
    __shared__ __attribute__((aligned(16))) unsigned short list[N_HID];
    __shared__ __attribute__((aligned(16))) unsigned char spk[1024];
    __shared__ int sh_n;
    __shared__ int sh_inact;

    const int b = blockIdx.x;
    const int t = threadIdx.x;           // 0..1023
    const int lane = t & 63;
    const int wave = t >> 6;

    float hm[4], csr[4];
    #pragma unroll
    for (int k = 0; k < 4; ++k) {
        hm[k]  = h_mem_g[(size_t)b * N_HID + 4 * t + k];
        csr[k] = cs_rec[4 * t + k];
    }
    float om  = o_mem_g[(size_t)b * N_OUT + t];
    float cso = cs_out[t];
    if (do_accum) {
        float s = 0.f;
        #pragma unroll
        for (int ks = 0; ks < KSPLIT; ++ks)
            s += out_part[(size_t)ks * B_SZ * N_OUT + (size_t)b * N_OUT + t];
        om = TAU * om + s;
        out[((size_t)b * T_SZ + (t0 + tloc0 - 1)) * N_OUT + t] = om;
    }
    if (t < 64) mask[t] = mask_g[b * 64 + t];
    __syncthreads();

    // previous-step spike flags for cols 4t..4t+3 (hard reset term)
    float spf[4];
    {
        unsigned long long w = mask[t >> 4];
        int sh = 4 * (t & 15);
        #pragma unroll
        for (int k = 0; k < 4; ++k)
            spf[k] = (float)((w >> (sh + k)) & 1ULL);
    }
    if (wave == 0) build_list_core(mask[lane], list, &sh_n, &sh_inact, lane);
    __syncthreads();

    const unsigned short* Wb = WrecB + 4 * t;
    const unsigned short* Wo = WoutB + t;

    // ---- prologue: rec gather for the FIRST step from the initial list ----
    float rec_cur[4];
    {
        int n = sh_n, inact = sh_inact;
        float a[8][4] = {};
        int i = 0;
        for (; i + 8 <= n; i += 8) {
            ush8 jv = *(const ush8*)&list[i];
            #pragma unroll
            for (int r = 0; r < 8; ++r) {
                uint2 v = *(const uint2*)(Wb + (size_t)jv[r] * N_HID);
                a[r][0] += __uint_as_float(v.x << 16);
                a[r][1] += __uint_as_float(v.x & 0xFFFF0000u);
                a[r][2] += __uint_as_float(v.y << 16);
                a[r][3] += __uint_as_float(v.y & 0xFFFF0000u);
            }
        }
        for (; i < n; ++i) {
            uint2 v = *(const uint2*)(Wb + (size_t)list[i] * N_HID);
            a[0][0] += __uint_as_float(v.x << 16);
            a[0][1] += __uint_as_float(v.x & 0xFFFF0000u);
            a[0][2] += __uint_as_float(v.y << 16);
            a[0][3] += __uint_as_float(v.y & 0xFFFF0000u);
        }
        #pragma unroll
        for (int k = 0; k < 4; ++k) {
            float racc = ((a[0][k] + a[1][k]) + (a[2][k] + a[3][k]))
                       + ((a[4][k] + a[5][k]) + (a[6][k] + a[7][k]));
            rec_cur[k] = REC_SCALE * (inact ? (csr[k] - racc) : racc);
        }
    }

    // prefetched input (double-buffered so HBM latency hides under the step)
    float4 ivq = *(const float4*)(inp + ((size_t)b * Tc + tloc0) * N_HID + 4 * t);

    for (int tl = 0; tl < nsteps; ++tl) {
        float4 iv_next = make_float4(0.f, 0.f, 0.f, 0.f);
        bool more = (tl + 1 < nsteps);
        if (more)
            iv_next = *(const float4*)(inp + ((size_t)b * Tc + tloc0 + tl + 1) * N_HID
                                       + 4 * t);

        // ---- membrane update + spike decision (rec_cur precomputed) ----
        float ivv[4] = {ivq.x, ivq.y, ivq.z, ivq.w};
        unsigned nib = 0;
        #pragma unroll
        for (int k = 0; k < 4; ++k) {
            float v = TAU * hm[k] * (1.0f - spf[k]) + (ivv[k] + rec_cur[k]);
            hm[k] = v;
            bool s = (v >= THRESH);
            spf[k] = s ? 1.0f : 0.0f;
            nib |= (s ? 1u : 0u) << k;
        }
        spk[t] = (unsigned char)nib;
        __syncthreads();   // B2: spk visible; orders prev gather's list reads
                           //     before this build's list writes
        if (wave == 0) {
            uint4 q = *(const uint4*)&spk[lane * 16];
            unsigned w0 = pack4(q.x) | (pack4(q.y) << 16);
            unsigned w1 = pack4(q.z) | (pack4(q.w) << 16);
            unsigned long long w = (unsigned long long)w0
                                 | ((unsigned long long)w1 << 32);
            mask[lane] = w;
            build_list_core(w, list, &sh_n, &sh_inact, lane);
        }
        __syncthreads();   // B3: list/counts ready

        // ---- FUSED gather over min side of NEW spikes:
        //      out contribution (this step) + rec input (next step) ----
        int n2 = sh_n, inact = sh_inact;
        float a[4][4] = {};
        float o4[4] = {0.f, 0.f, 0.f, 0.f};
        int i = 0;
        for (; i + 4 <= n2; i += 4) {
            ush4 jv = *(const ush4*)&list[i];
            #pragma unroll
            for (int r = 0; r < 4; ++r) {
                uint2 v = *(const uint2*)(Wb + (size_t)jv[r] * N_HID);
                o4[r] += bf2f(Wo[(size_t)jv[r] * N_OUT]);
                a[r][0] += __uint_as_float(v.x << 16);
                a[r][1] += __uint_as_float(v.x & 0xFFFF0000u);
                a[r][2] += __uint_as_float(v.y << 16);
                a[r][3] += __uint_as_float(v.y & 0xFFFF0000u);
            }
        }
        for (; i < n2; ++i) {
            int j = list[i];
            uint2 v = *(const uint2*)(Wb + (size_t)j * N_HID);
            o4[0] += bf2f(Wo[(size_t)j * N_OUT]);
            a[0][0] += __uint_as_float(v.x << 16);
            a[0][1] += __uint_as_float(v.x & 0xFFFF0000u);
            a[0][2] += __uint_as_float(v.y << 16);
            a[0][3] += __uint_as_float(v.y & 0xFFFF0000u);
        }
        float oacc = (o4[0] + o4[1]) + (o4[2] + o4[3]);
        om = TAU * om + (inact ? (cso - oacc) : oacc);
        out[((size_t)b * T_SZ + (t0 + tloc0 + tl)) * N_OUT + t] = om;
        #pragma unroll
        for (int k = 0; k < 4; ++k) {
            float racc = (a[0][k] + a[1][k]) + (a[2][k] + a[3][k]);
            rec_cur[k] = REC_SCALE * (inact ? (csr[k] - racc) : racc);
        }

        if (more) ivq = iv_next;
    }

    #pragma unroll
    for (int k = 0; k < 4; ++k)
        h_mem_g[(size_t)b * N_HID + 4 * t + k] = hm[k];
    o_mem_g[(size_t)b * N_OUT + t] = om;
    __syncthreads();
    if (t < 64) mask_g[b * 64 + t] = mask[t];
}

// ---------------------------------------------------------------------------
extern "C" void kernel_launch(void* const* d_in, const int* in_sizes, int n_in,
                              void* d_out, int out_size, void* d_ws, size_t ws_size,
                              hipStream_t stream) {
    const float* x    = (const float*)d_in[0];
    const float* Wfc1 = (const float*)d_in[1];
    const float* Wrec = (const float*)d_in[2];
    const float* Wout = (const float*)d_in[3];
    float* out = (float*)d_out;

    // workspace layout (all 16B-aligned)
    float* h_mem = (float*)d_ws;                               // 2 MB
    float* o_mem = h_mem + B_SZ * N_HID;                       // 0.5 MB
    unsigned long long* maskg =
        (unsigned long long*)(o_mem + B_SZ * N_OUT);           // 64 KB
    float* cs_rec = (float*)(maskg + B_SZ * 64);               // 16 KB
    float* cs_out = cs_rec + N_HID;                            // 4 KB
    unsigned short* WrecB = (unsigned short*)(cs_out + N_OUT); // 33.55 MB
    unsigned short* WoutB = WrecB + (size_t)N_HID * N_HID;     // 8.39 MB
    unsigned short* WrecT = WoutB + (size_t)N_HID * N_OUT;     // 33.55 MB
    unsigned short* WoutT = WrecT + (size_t)N_HID * N_HID;     // 8.39 MB
    char* Bt = (char*)(WoutT + (size_t)N_OUT * N_HID);         // 8.39 MB (i8)
    unsigned short* spk = (unsigned short*)(Bt + (size_t)N_HID * 2048); // 1.05 MB
    float* rec_part = (float*)(spk + (size_t)B_SZ * N_HID);    // 16.78 MB
    float* out_part = rec_part + (size_t)KSPLIT * B_SZ * N_HID;// 4.19 MB
    char* Ax = (char*)(out_part + (size_t)KSPLIT * B_SZ * N_OUT);
    // inp_chunk follows Ax (Tc-dependent)

    size_t fixed_bytes = (size_t)(B_SZ * N_HID + B_SZ * N_OUT) * 4
                       + (size_t)B_SZ * 64 * 8
                       + (size_t)(N_HID + N_OUT) * 4
                       + 2 * (size_t)N_HID * N_HID * 2          // WrecB + WrecT
                       + 2 * (size_t)N_HID * N_OUT * 2          // WoutB + WoutT
                       + (size_t)N_HID * 2048                   // Bt (int8)
                       + (size_t)B_SZ * N_HID * 2               // spk
                       + (size_t)KSPLIT * B_SZ * (N_HID + N_OUT) * 4;
    int Tc = 64;
    while (Tc > 8 &&
           fixed_bytes + (size_t)Tc * (B_SZ * 2048 + B_SZ * N_HID * 4) > ws_size)
        Tc >>= 1;
    float* inp_chunk = (float*)(Ax + (size_t)B_SZ * Tc * 2048);

    int state_floats = B_SZ * N_HID + B_SZ * N_OUT + B_SZ * 64 * 2;
    zero_state_kernel<<<256, 256, 0, stream>>>(h_mem, state_floats);
    // fused bf16 copy + transpose (one read of each weight matrix)
    convT_bf16_kernel<<<dim3(N_HID / 64, N_HID / 64), 256, 0, stream>>>(
        Wrec, WrecB, WrecT, N_HID, N_HID);
    convT_bf16_kernel<<<dim3(N_OUT / 64, N_HID / 64), 256, 0, stream>>>(
        Wout, WoutB, WoutT, N_HID, N_OUT);
    colsum_bf16_kernel<<<80, 256, 0, stream>>>(WrecB, WoutB, cs_rec, cs_out);
    convert_w_kernel<<<dim3(32, 64), 256, 0, stream>>>(Wfc1, Bt);

    for (int t0 = 0; t0 < T_SZ; t0 += Tc) {
        convert_x_kernel<<<2048, 256, 0, stream>>>(x, Ax, t0, Tc);
        int my = (B_SZ * Tc) / 128;   // multiple of 8 for Tc >= 8
        fc1_mfma_kernel<<<32 * my, 256, 0, stream>>>(Ax, Bt, inp_chunk, my);

        if (t0 == 0) {
            // dense transient: steps 0..S_DENSE-1, two dispatches per step
            for (int tg = 0; tg < S_DENSE; ++tg) {
                transient_update_kernel<<<B_SZ * 4, 256, 0, stream>>>(
                    inp_chunk, rec_part, out_part, h_mem, o_mem, spk, maskg, out,
                    tg, Tc, /*has_rec=*/tg > 0, /*has_out=*/tg > 0);
                int do_rec = (tg + 1 < S_DENSE);
                spk_gemm_merged_kernel<<<do_rec ? 320 : 64, 256, 0, stream>>>(
                    spk, WrecT, WoutT, rec_part, out_part, do_rec);
            }
            rsnn_step_kernel<<<B_SZ, 1024, 0, stream>>>(
                inp_chunk, WrecB, WoutB, cs_rec, cs_out, out_part,
                h_mem, o_mem, maskg, out,
                t0, Tc, /*tloc0=*/S_DENSE, /*nsteps=*/Tc - S_DENSE, /*do_accum=*/1);
        } else {
            rsnn_step_kernel<<<B_SZ, 1024, 0, stream>>>(
                inp_chunk, WrecB, WoutB, cs_rec, cs_out, out_part,
                h_mem, o_mem, maskg, out,
                t0, Tc, /*tloc0=*/0, /*nsteps=*/Tc, /*do_accum=*/0);
        }
    }
}

// Round 8
// 569.919 us; speedup vs baseline: 1.0133x; 1.0129x over previous
//
#include <hip/hip_runtime.h>
#include <stdint.h>

#define B_SZ 128
#define T_SZ 64
#define N_IN 1024
#define N_HID 4096
#define N_OUT 1024
#define TAU 0.9f
#define THRESH 0.5f
#define REC_SCALE 0.1f
#define S_DENSE 5          // steps 0..4 computed via dense MFMA GEMMs
#define KSPLIT 8           // K-split for spk GEMMs (4096/8 = 512 per chunk)

typedef __attribute__((ext_vector_type(8))) short sh8;
typedef __attribute__((ext_vector_type(4))) float f32x4;
typedef __attribute__((ext_vector_type(4))) int i32x4;
typedef __attribute__((ext_vector_type(4))) unsigned short ush4;
typedef __attribute__((ext_vector_type(8))) unsigned short ush8;

// ---------------------------------------------------------------------------
// helpers
// ---------------------------------------------------------------------------
__device__ __forceinline__ unsigned short f2bf_rn(float f) {
    unsigned u = __float_as_uint(f);
    unsigned r = (u + 0x7FFFu + ((u >> 16) & 1u)) >> 16;
    return (unsigned short)r;
}
__device__ __forceinline__ float bf2f(unsigned short h) {
    return __uint_as_float((unsigned)h << 16);
}
__device__ __forceinline__ void gload_lds16(const void* g, void* l) {
    __builtin_amdgcn_global_load_lds(
        (const __attribute__((address_space(1))) void*)g,
        (__attribute__((address_space(3))) void*)l, 16, 0, 0);
}
// compress low nibbles of 4 bytes into 16 bits
__device__ __forceinline__ unsigned pack4(unsigned a) {
    a &= 0x0F0F0F0Fu;
    a = (a | (a >> 4)) & 0x00FF00FFu;
    a = (a | (a >> 8)) & 0x0000FFFFu;
    return a;
}

// ---------------------------------------------------------------------------
__global__ void zero_state_kernel(float* p, int n) {
    int i = blockIdx.x * blockDim.x + threadIdx.x;
    int stride = gridDim.x * blockDim.x;
    for (; i < n; i += stride) p[i] = 0.0f;
}

// ---------------------------------------------------------------------------
// fused: W [R][C] fp32 -> WB [R][C] bf16 AND WT [C][R] bf16 (one read of W)
// ---------------------------------------------------------------------------
__global__ __launch_bounds__(256)
void convT_bf16_kernel(const float* __restrict__ W,
                       unsigned short* __restrict__ WB,
                       unsigned short* __restrict__ WT, int R, int C) {
    __shared__ float ts[64][65];
    int tid = threadIdx.x;
    int c0 = blockIdx.x * 64;
    int r0 = blockIdx.y * 64;
    #pragma unroll
    for (int rr = 0; rr < 16; ++rr) {
        int r = rr * 4 + (tid >> 6);
        int c = tid & 63;
        float v = W[(size_t)(r0 + r) * C + c0 + c];
        ts[r][c] = v;
        WB[(size_t)(r0 + r) * C + c0 + c] = f2bf_rn(v);
    }
    __syncthreads();
    #pragma unroll
    for (int rr = 0; rr < 16; ++rr) {
        int c = rr * 4 + (tid >> 6);
        int r = tid & 63;
        WT[(size_t)(c0 + c) * R + r0 + r] = f2bf_rn(ts[r][c]);
    }
}

// ---------------------------------------------------------------------------
// column sums of the bf16-rounded W_rec / W_out (for the sparse complement)
// ---------------------------------------------------------------------------
__global__ __launch_bounds__(256)
void colsum_bf16_kernel(const unsigned short* __restrict__ WrecB,
                        const unsigned short* __restrict__ WoutB,
                        float* __restrict__ cs_rec, float* __restrict__ cs_out) {
    __shared__ float part[4][64];
    int tid = threadIdx.x;
    int c = tid & 63, q = tid >> 6;
    int col = blockIdx.x * 64 + c;  // 0..5119
    float s = 0.f;
    if (col < N_HID) {
        const unsigned short* p = WrecB + col + (size_t)q * 1024 * N_HID;
        for (int j = 0; j < 1024; ++j) s += bf2f(p[(size_t)j * N_HID]);
    } else {
        int o = col - N_HID;
        const unsigned short* p = WoutB + o + (size_t)q * 1024 * N_OUT;
        for (int j = 0; j < 1024; ++j) s += bf2f(p[(size_t)j * N_OUT]);
    }
    part[q][c] = s;
    __syncthreads();
    if (tid < 64) {
        float tot = part[0][tid] + part[1][tid] + part[2][tid] + part[3][tid];
        int col2 = blockIdx.x * 64 + tid;
        if (col2 < N_HID) cs_rec[col2] = tot;
        else              cs_out[col2 - N_HID] = tot;
    }
}

// ---------------------------------------------------------------------------
// x [B,T,1024] fp32 -> Ax [128*Tc][2048] int8 limbs: cols 0..1023 = X1 (high
// 6 bits), 1024..2047 = X0 (low 7 bits); x ~= 2^-13 * (X1*128 + X0).
// ---------------------------------------------------------------------------
__global__ __launch_bounds__(256)
void convert_x_kernel(const float* __restrict__ x, char* __restrict__ Ax,
                      int t0, int Tc) {
    int total4 = B_SZ * Tc * (N_IN / 4);
    int i = blockIdx.x * blockDim.x + threadIdx.x;
    int stride = gridDim.x * blockDim.x;
    for (; i < total4; i += stride) {
        int m = i >> 8;
        int c4 = i & 255;
        int b = m / Tc, tl = m - b * Tc;
        float4 v = *(const float4*)(x + ((size_t)(b * T_SZ + t0 + tl) * N_IN) + c4 * 4);
        float f[4] = {v.x, v.y, v.z, v.w};
        char hi[4], lo[4];
        #pragma unroll
        for (int j = 0; j < 4; ++j) {
            int X = (int)rintf(f[j] * 8192.0f);
            X = X < 0 ? 0 : (X > 8191 ? 8191 : X);
            hi[j] = (char)(X >> 7);          // 0..63
            lo[j] = (char)(X & 127);         // 0..127
        }
        char* row = Ax + (size_t)m * 2048;
        *(char4*)(row + c4 * 4)        = *(const char4*)hi;
        *(char4*)(row + 1024 + c4 * 4) = *(const char4*)lo;
    }
}

// ---------------------------------------------------------------------------
// W_fc1 [1024][4096] fp32 -> Bt [4096][2048] int8 limbs, transposed:
// cols 0..1023 = V1, 1024..2047 = V0; W ~= 2^-19 * (V1*128 + V0).
// ---------------------------------------------------------------------------
__global__ __launch_bounds__(256)
void convert_w_kernel(const float* __restrict__ W, char* __restrict__ Bt) {
    __shared__ float ts[32][65];
    int tid = threadIdx.x;
    int k0 = blockIdx.x * 32;
    int n0 = blockIdx.y * 64;
    #pragma unroll
    for (int rr = 0; rr < 8; ++rr) {
        int kl = (tid >> 6) * 8 + rr;
        int nl = tid & 63;
        ts[kl][nl] = W[(size_t)(k0 + kl) * N_HID + n0 + nl];
    }
    __syncthreads();
    #pragma unroll
    for (int rr = 0; rr < 8; ++rr) {
        int nl = (tid >> 5) + rr * 8;
        int kl = tid & 31;
        float v = ts[kl][nl];
        int V = (int)rintf(v * 524288.0f);
        V = V < -16383 ? -16383 : (V > 16383 ? 16383 : V);
        char* row = Bt + (size_t)(n0 + nl) * 2048;
        row[k0 + kl]        = (char)(V >> 7);   // -128..127
        row[1024 + k0 + kl] = (char)(V & 127);  // 0..127
    }
}

// ---------------------------------------------------------------------------
// fc1 GEMM via int8 MFMA, virtual K = 3072 (X0*V0 dropped, sigma~2e-5):
//   tiles  0..15: X1 * V1   -> acc <<= 7 after tile 15
//   tiles 16..47: [X1|X0] * [V0|V1] cross terms
//   C = 2^-25 * (float)acc
// T3/T4 counted-vmcnt pipeline (round-8 hardened resubmit of round 7):
// 4 LDS buffers, 3 tiles in flight, per iteration
//     s_waitcnt vmcnt(8)  (one asm instr — my tile-t loads FIFO-retired,
//                          8 newer ops for t+1/t+2 stay outstanding)
//     sched_barrier(0)    (rule #18: no reordering across the wait)
//     __builtin_amdgcn_s_barrier()   (compiler-visible barrier, no implicit
//                          waitcnt — the m201-verified idiom, NOT asm s_barrier)
// Safety: per-wave ds_reads of a buffer complete before that wave's MFMA
// (compiler lgkmcnt) hence before its next barrier; stage into buf (t+3)&3
// follows the barrier after compute(t-1) of that same buffer; wait-before-
// barrier makes tile-t loads of ALL waves visible. Tail prefetches clamp to
// tile 47 and land in buffers never read again. Compute order unchanged ->
// bitwise-identical C.
// ---------------------------------------------------------------------------
__global__ __launch_bounds__(256)
void fc1_mfma_kernel(const char* __restrict__ A,
                     const char* __restrict__ Bt,
                     float* __restrict__ C, int my) {
    __shared__ __attribute__((aligned(16))) char As[4][128 * 64];
    __shared__ __attribute__((aligned(16))) char Bs[4][128 * 64];
    const int tid = threadIdx.x;
    const int lane = tid & 63;
    const int wave = tid >> 6;
    const int wm = (wave >> 1) * 64;   // waves 2(M) x 2(N)
    const int wn = (wave & 1) * 64;
    const int quad = lane >> 4, l16 = lane & 15;

    // XCD swizzle: XCD k owns m-tiles [k*my/8, (k+1)*my/8), n varies outer.
    const int lin = blockIdx.x;
    const int ych = my >> 3;                 // my % 8 == 0 guaranteed
    const int xcd = lin & 7, rel = lin >> 3;
    const int m0 = (xcd * ych + (rel % ych)) * 128;
    const int n0 = (rel / ych) * 128;

    const char* aptr[2];
    const char* bptr[2];
    int loff[2];
    #pragma unroll
    for (int i = 0; i < 2; ++i) {
        int idx = i * 256 + tid;             // 0..511 -> row=idx>>2, ch=idx&3
        int row = idx >> 2, ch = idx & 3;
        int g = (ch - (row >> 1)) & 3;       // inverse rotation on global src
        aptr[i] = A  + (size_t)(m0 + row) * 2048 + g * 16;
        bptr[i] = Bt + (size_t)(n0 + row) * 2048 + g * 16;
        loff[i] = idx * 16;                  // linear LDS dest (DMA constraint)
    }

    // loop-invariant fragment LDS byte offsets (rotated chunk addressing)
    int offA[4], offB[4];
    #pragma unroll
    for (int mt = 0; mt < 4; ++mt) {
        int ra = wm + mt * 16 + l16;
        offA[mt] = ra * 64 + (((quad + (ra >> 1)) & 3) << 4);
        int rb = wn + mt * 16 + l16;
        offB[mt] = rb * 64 + (((quad + (rb >> 1)) & 3) << 4);
    }

    i32x4 acc[4][4] = {};

    // stage virtual tile t (0..47) into LDS buffer buf; t clamped so the
    // tail prefetches stay in-bounds (the extra loads land in a buffer that
    // is never computed again).
    auto stage_t = [&](int buf, int t) {
        int tt = t < 47 ? t : 47;
        int ak = (tt < 16 ? tt : tt - 16) * 64;
        int bk = (tt < 16) ? ak : ((ak + 1024) & 2047);
        gload_lds16(aptr[0] + ak, &As[buf][loff[0]]);
        gload_lds16(aptr[1] + ak, &As[buf][loff[1]]);
        gload_lds16(bptr[0] + bk, &Bs[buf][loff[0]]);
        gload_lds16(bptr[1] + bk, &Bs[buf][loff[1]]);
    };
    auto compute = [&](int buf) {
        const char* ca = As[buf];
        const char* cb = Bs[buf];
        i32x4 af[4], bf[4];
        #pragma unroll
        for (int mt = 0; mt < 4; ++mt) af[mt] = *(const i32x4*)(ca + offA[mt]);
        #pragma unroll
        for (int nt = 0; nt < 4; ++nt) bf[nt] = *(const i32x4*)(cb + offB[nt]);
        #pragma unroll
        for (int mt = 0; mt < 4; ++mt)
            #pragma unroll
            for (int nt = 0; nt < 4; ++nt)
                acc[mt][nt] = __builtin_amdgcn_mfma_i32_16x16x64_i8(
                    af[mt], bf[nt], acc[mt][nt], 0, 0, 0);
    };
    // counted wait + compiler-visible barrier (verified idiom: m201 template)
    auto wb = [&]() {
        asm volatile("s_waitcnt vmcnt(8)" ::: "memory");
        __builtin_amdgcn_sched_barrier(0);
        __builtin_amdgcn_s_barrier();
    };

    // prologue: 3 tiles in flight
    stage_t(0, 0);
    stage_t(1, 1);
    stage_t(2, 2);

    // ---- segment 1: X1 * V1 (tiles 0..15) ----
    #pragma unroll 4
    for (int t = 0; t < 16; ++t) {
        wb();
        stage_t((t + 3) & 3, t + 3);
        compute(t & 3);
    }

    // ---- scale hi-limb partial by 128 (exact) ----
    #pragma unroll
    for (int mt = 0; mt < 4; ++mt)
        #pragma unroll
        for (int nt = 0; nt < 4; ++nt)
            #pragma unroll
            for (int r = 0; r < 4; ++r)
                acc[mt][nt][r] <<= 7;

    // ---- segment 2: cross terms (tiles 16..47) ----
    #pragma unroll 4
    for (int t = 16; t < 48; ++t) {
        wb();
        stage_t((t + 3) & 3, t + 3);
        compute(t & 3);
    }

    #pragma unroll
    for (int mt = 0; mt < 4; ++mt)
        #pragma unroll
        for (int nt = 0; nt < 4; ++nt) {
            int col = n0 + wn + nt * 16 + l16;
            #pragma unroll
            for (int r = 0; r < 4; ++r) {
                int m = m0 + wm + mt * 16 + quad * 4 + r;
                C[(size_t)m * N_HID + col] = 0x1p-25f * (float)acc[mt][nt][r];
            }
        }
}

// ---------------------------------------------------------------------------
// One 128x128 C-tile of part[ks][128][Nfull] = spk[128][4096] @ BT[...]^T over
// a 512-wide K chunk. Hoisted fragment offsets, branch-free unrolled loop
// with literal buffer indices (verified structure — unchanged).
// ---------------------------------------------------------------------------
__device__ __forceinline__ void spk_tile_gemm(const unsigned short* __restrict__ A,
                                              const unsigned short* __restrict__ BT,
                                              float* __restrict__ part, int Nfull,
                                              int nt, int ks,
                                              unsigned short (*As)[128 * 32],
                                              unsigned short (*Bs)[128 * 32],
                                              int tid) {
    const int lane = tid & 63;
    const int wave = tid >> 6;
    const int wm = (wave >> 1) * 64;
    const int wn = (wave & 1) * 64;
    const int quad = lane >> 4, l16 = lane & 15;
    const int n0 = nt * 128;
    const int k0 = ks * (N_HID / KSPLIT);

    const unsigned short* aptr[2];
    const unsigned short* bptr[2];
    int loff[2];
    #pragma unroll
    for (int i = 0; i < 2; ++i) {
        int idx = tid + 256 * i;
        int row = idx >> 2, cg = idx & 3;
        int g = (cg - (row >> 1)) & 3;       // inverse rotation on global src
        aptr[i] = A  + (size_t)row * N_HID + k0 + g * 8;
        bptr[i] = BT + (size_t)(n0 + row) * N_HID + k0 + g * 8;
        loff[i] = idx * 8;
    }

    // loop-invariant fragment LDS offsets (in shorts)
    int offA[4], offB[4];
    #pragma unroll
    for (int mt = 0; mt < 4; ++mt) {
        int ra = wm + mt * 16 + l16;
        offA[mt] = ra * 32 + (((quad + (ra >> 1)) & 3) << 3);
        int rb = wn + mt * 16 + l16;
        offB[mt] = rb * 32 + (((quad + (rb >> 1)) & 3) << 3);
    }

    f32x4 acc[4][4] = {};

    auto stage = [&](int buf, int kk) {
        gload_lds16(aptr[0] + kk, &As[buf][loff[0]]);
        gload_lds16(aptr[1] + kk, &As[buf][loff[1]]);
        gload_lds16(bptr[0] + kk, &Bs[buf][loff[0]]);
        gload_lds16(bptr[1] + kk, &Bs[buf][loff[1]]);
    };
    auto compute = [&](int buf) {
        const unsigned short* ca = As[buf];
        const unsigned short* cb = Bs[buf];
        sh8 af[4], bf[4];
        #pragma unroll
        for (int mt = 0; mt < 4; ++mt) af[mt] = *(const sh8*)(ca + offA[mt]);
        #pragma unroll
        for (int nt2 = 0; nt2 < 4; ++nt2) bf[nt2] = *(const sh8*)(cb + offB[nt2]);
        #pragma unroll
        for (int mt = 0; mt < 4; ++mt)
            #pragma unroll
            for (int nt2 = 0; nt2 < 4; ++nt2)
                acc[mt][nt2] = __builtin_amdgcn_mfma_f32_16x16x32_bf16(
                    af[mt], bf[nt2], acc[mt][nt2], 0, 0, 0);
    };

    stage(0, 0);
    __syncthreads();
    #pragma unroll 2
    for (int kt = 0; kt < 15; ++kt) {            // 16 K-tiles total
        stage((kt + 1) & 1, (kt + 1) * 32);
        compute(kt & 1);
        __syncthreads();
    }
    compute(1);                                   // kt = 15

    float* pout = part + (size_t)ks * 128 * Nfull;
    #pragma unroll
    for (int mt = 0; mt < 4; ++mt)
        #pragma unroll
        for (int nt2 = 0; nt2 < 4; ++nt2) {
            int col = n0 + wn + nt2 * 16 + l16;
            #pragma unroll
            for (int r = 0; r < 4; ++r) {
                int m = wm + mt * 16 + quad * 4 + r;
                pout[(size_t)m * Nfull + col] = acc[mt][nt2][r];
            }
        }
}

// ---------------------------------------------------------------------------
// Merged per-step spk GEMMs: one dispatch computes BOTH the rec partials
// (blocks 0..255: 32 n-tiles x 8 ksplit) and the out partials (blocks
// 256..319: 8 n-tiles x 8 ksplit). When do_rec==0 (last dense step), grid=64
// and all blocks do out tiles. No grid-wide sync anywhere.
// ---------------------------------------------------------------------------
__global__ __launch_bounds__(256)
void spk_gemm_merged_kernel(const unsigned short* __restrict__ spk,
                            const unsigned short* __restrict__ WrecT,
                            const unsigned short* __restrict__ WoutT,
                            float* __restrict__ rec_part,
                            float* __restrict__ out_part,
                            int do_rec) {
    __shared__ __attribute__((aligned(16))) unsigned short As[2][128 * 32];
    __shared__ __attribute__((aligned(16))) unsigned short Bs[2][128 * 32];
    const int bid = blockIdx.x;
    const int tid = threadIdx.x;
    if (do_rec) {
        if (bid < 256)
            spk_tile_gemm(spk, WrecT, rec_part, N_HID, bid & 31, bid >> 5, As, Bs, tid);
        else {
            int o = bid - 256;
            spk_tile_gemm(spk, WoutT, out_part, N_OUT, o & 7, o >> 3, As, Bs, tid);
        }
    } else {
        spk_tile_gemm(spk, WoutT, out_part, N_OUT, bid & 7, bid >> 3, As, Bs, tid);
    }
}

// ---------------------------------------------------------------------------
// Transient pointwise step. grid = 512 (4 blocks per batch, quarter each),
// 256 threads. Thread (q,tid) owns t4 = q*256+tid: h cols 4*t4..4*t4+3 and
// o col t4.
// ---------------------------------------------------------------------------
__global__ __launch_bounds__(256)
void transient_update_kernel(const float* __restrict__ inp,      // [B][Tc][N_HID]
                             const float* __restrict__ rec_part, // [KSPLIT][B][N_HID]
                             const float* __restrict__ out_part, // [KSPLIT][B][N_OUT]
                             float* __restrict__ h_mem,
                             float* __restrict__ o_mem,
                             unsigned short* __restrict__ spk,   // [B][N_HID] bf16
                             unsigned long long* __restrict__ maskg,
                             float* __restrict__ out,
                             int t_glob, int Tc, int has_rec, int has_out) {
    __shared__ __attribute__((aligned(16))) unsigned char spkb[256];
    const int b = blockIdx.x >> 2;
    const int q = blockIdx.x & 3;
    const int tid = threadIdx.x;
    const int t4 = q * 256 + tid;

    if (has_out) {
        float s = 0.f;
        #pragma unroll
        for (int ks = 0; ks < KSPLIT; ++ks)
            s += out_part[(size_t)ks * B_SZ * N_OUT + (size_t)b * N_OUT + t4];
        float o = TAU * o_mem[(size_t)b * N_OUT + t4] + s;
        o_mem[(size_t)b * N_OUT + t4] = o;
        out[((size_t)b * T_SZ + (t_glob - 1)) * N_OUT + t4] = o;
    }

    float rec[4] = {0.f, 0.f, 0.f, 0.f};
    if (has_rec) {
        #pragma unroll
        for (int ks = 0; ks < KSPLIT; ++ks) {
            float4 p = *(const float4*)(rec_part + (size_t)ks * B_SZ * N_HID
                                        + (size_t)b * N_HID + 4 * t4);
            rec[0] += p.x; rec[1] += p.y; rec[2] += p.z; rec[3] += p.w;
        }
    }

    unsigned short* sp = spk + (size_t)b * N_HID + 4 * t4;
    ush4 prev = *(const ush4*)sp;    // bf16 {0,1}; t_glob=0: h=0 so unused
    float4 iv = *(const float4*)(inp + ((size_t)b * Tc + t_glob) * N_HID + 4 * t4);
    float ivv[4] = {iv.x, iv.y, iv.z, iv.w};
    float* hp = h_mem + (size_t)b * N_HID + 4 * t4;
    float hv[4] = {hp[0], hp[1], hp[2], hp[3]};
    ush4 news;
    unsigned nib = 0;
    #pragma unroll
    for (int k = 0; k < 4; ++k) {
        float spf = bf2f(prev[k]);
        float v = TAU * hv[k] * (1.0f - spf) + (ivv[k] + REC_SCALE * rec[k]);
        hp[k] = v;
        bool s = (v >= THRESH);
        news[k] = s ? (unsigned short)0x3F80 : (unsigned short)0;
        nib |= (s ? 1u : 0u) << k;
    }
    *(ush4*)sp = news;
    spkb[tid] = (unsigned char)nib;
    __syncthreads();
    if (tid < 16) {
        uint4 qd = *(const uint4*)&spkb[tid * 16];
        unsigned w0 = pack4(qd.x) | (pack4(qd.y) << 16);
        unsigned w1 = pack4(qd.z) | (pack4(qd.w) << 16);
        maskg[b * 64 + q * 16 + tid] = (unsigned long long)w0
                                     | ((unsigned long long)w1 << 32);
    }
}

// ---------------------------------------------------------------------------
// min-side list build from a 64-bit word per lane (wave 0 only).
// ---------------------------------------------------------------------------
__device__ __forceinline__ void build_list_core(unsigned long long w,
                                                unsigned short* list,
                                                int* sh_n, int* sh_inact,
                                                int lane) {
    int tot = __builtin_popcountll(w);
    #pragma unroll
    for (int d = 32; d > 0; d >>= 1) tot += __shfl_xor(tot, d, 64);
    int inact = tot > (N_HID / 2);
    unsigned long long wsel = inact ? ~w : w;
    int c = __builtin_popcountll(wsel);
    int scan = c;
    #pragma unroll
    for (int d = 1; d < 64; d <<= 1) {
        int v = __shfl_up(scan, d, 64);
        if (lane >= d) scan += v;
    }
    int off = scan - c;
    while (wsel) {
        int bpos = __builtin_ctzll(wsel);
        list[off++] = (unsigned short)(lane * 64 + bpos);
        wsel &= wsel - 1;
    }
    if (lane == 0) {
        *sh_n = inact ? (N_HID - tot) : tot;
        *sh_inact = inact;
    }
}

// ---------------------------------------------------------------------------
// Sparse RSNN step loop for steps tloc0..tloc0+nsteps-1 of the current chunk.
// Fused gather (round 5): out contribution of step t and rec input of step
// t+1 read the same list; 2 barriers/step.
// ---------------------------------------------------------------------------
__global__ __launch_bounds__(1024, 4)
void rsnn_step_kernel(const float* __restrict__ inp,            // [B][Tc][N_HID]
                      const unsigned short* __restrict__ WrecB, // [N_HID][N_HID] bf16
                      const unsigned short* __restrict__ WoutB, // [N_HID][N_OUT] bf16
                      const float* __restrict__ cs_rec,
                      const float* __restrict__ cs_out,
                      const float* __restrict__ out_part,       // [KSPLIT][B][N_OUT]
                      float* __restrict__ h_mem_g,
                      float* __restrict__ o_mem_g,
                      unsigned long long* __restrict__ mask_g,
                      float* __restrict__ out,
                      int t0, int Tc, int tloc0, int nsteps, int do_accum) {
    __shared__ unsigned long long mask[64];
    __shared__ __attribute__((aligned(16))) unsigned short list[N_HID];
    __shared__ __attribute__((aligned(16))) unsigned char spk[1024];
    __shared__ int sh_n;
    __shared__ int sh_inact;

    const int b = blockIdx.x;
    const int t = threadIdx.x;           // 0..1023
    const int lane = t & 63;
    const int wave = t >> 6;

    float hm[4], csr[4];
    #pragma unroll
    for (int k = 0; k < 4; ++k) {
        hm[k]  = h_mem_g[(size_t)b * N_HID + 4 * t + k];
        csr[k] = cs_rec[4 * t + k];
    }
    float om  = o_mem_g[(size_t)b * N_OUT + t];
    float cso = cs_out[t];
    if (do_accum) {
        float s = 0.f;
        #pragma unroll
        for (int ks = 0; ks < KSPLIT; ++ks)
            s += out_part[(size_t)ks * B_SZ * N_OUT + (size_t)b * N_OUT + t];
        om = TAU * om + s;
        out[((size_t)b * T_SZ + (t0 + tloc0 - 1)) * N_OUT + t] = om;
    }
    if (t < 64) mask[t] = mask_g[b * 64 + t];
    __syncthreads();

    // previous-step spike flags for cols 4t..4t+3 (hard reset term)
    float spf[4];
    {
        unsigned long long w = mask[t >> 4];
        int sh = 4 * (t & 15);
        #pragma unroll
        for (int k = 0; k < 4; ++k)
            spf[k] = (float)((w >> (sh + k)) & 1ULL);
    }
    if (wave == 0) build_list_core(mask[lane], list, &sh_n, &sh_inact, lane);
    __syncthreads();

    const unsigned short* Wb = WrecB + 4 * t;
    const unsigned short* Wo = WoutB + t;

    // ---- prologue: rec gather for the FIRST step from the initial list ----
    float rec_cur[4];
    {
        int n = sh_n, inact = sh_inact;
        float a[8][4] = {};
        int i = 0;
        for (; i + 8 <= n; i += 8) {
            ush8 jv = *(const ush8*)&list[i];
            #pragma unroll
            for (int r = 0; r < 8; ++r) {
                uint2 v = *(const uint2*)(Wb + (size_t)jv[r] * N_HID);
                a[r][0] += __uint_as_float(v.x << 16);
                a[r][1] += __uint_as_float(v.x & 0xFFFF0000u);
                a[r][2] += __uint_as_float(v.y << 16);
                a[r][3] += __uint_as_float(v.y & 0xFFFF0000u);
            }
        }
        for (; i < n; ++i) {
            uint2 v = *(const uint2*)(Wb + (size_t)list[i] * N_HID);
            a[0][0] += __uint_as_float(v.x << 16);
            a[0][1] += __uint_as_float(v.x & 0xFFFF0000u);
            a[0][2] += __uint_as_float(v.y << 16);
            a[0][3] += __uint_as_float(v.y & 0xFFFF0000u);
        }
        #pragma unroll
        for (int k = 0; k < 4; ++k) {
            float racc = ((a[0][k] + a[1][k]) + (a[2][k] + a[3][k]))
                       + ((a[4][k] + a[5][k]) + (a[6][k] + a[7][k]));
            rec_cur[k] = REC_SCALE * (inact ? (csr[k] - racc) : racc);
        }
    }

    // prefetched input (double-buffered so HBM latency hides under the step)
    float4 ivq = *(const float4*)(inp + ((size_t)b * Tc + tloc0) * N_HID + 4 * t);

    for (int tl = 0; tl < nsteps; ++tl) {
        float4 iv_next = make_float4(0.f, 0.f, 0.f, 0.f);
        bool more = (tl + 1 < nsteps);
        if (more)
            iv_next = *(const float4*)(inp + ((size_t)b * Tc + tloc0 + tl + 1) * N_HID
                                       + 4 * t);

        // ---- membrane update + spike decision (rec_cur precomputed) ----
        float ivv[4] = {ivq.x, ivq.y, ivq.z, ivq.w};
        unsigned nib = 0;
        #pragma unroll
        for (int k = 0; k < 4; ++k) {
            float v = TAU * hm[k] * (1.0f - spf[k]) + (ivv[k] + rec_cur[k]);
            hm[k] = v;
            bool s = (v >= THRESH);
            spf[k] = s ? 1.0f : 0.0f;
            nib |= (s ? 1u : 0u) << k;
        }
        spk[t] = (unsigned char)nib;
        __syncthreads();   // B2: spk visible; orders prev gather's list reads
                           //     before this build's list writes
        if (wave == 0) {
            uint4 q = *(const uint4*)&spk[lane * 16];
            unsigned w0 = pack4(q.x) | (pack4(q.y) << 16);
            unsigned w1 = pack4(q.z) | (pack4(q.w) << 16);
            unsigned long long w = (unsigned long long)w0
                                 | ((unsigned long long)w1 << 32);
            mask[lane] = w;
            build_list_core(w, list, &sh_n, &sh_inact, lane);
        }
        __syncthreads();   // B3: list/counts ready

        // ---- FUSED gather over min side of NEW spikes:
        //      out contribution (this step) + rec input (next step) ----
        int n2 = sh_n, inact = sh_inact;
        float a[4][4] = {};
        float o4[4] = {0.f, 0.f, 0.f, 0.f};
        int i = 0;
        for (; i + 4 <= n2; i += 4) {
            ush4 jv = *(const ush4*)&list[i];
            #pragma unroll
            for (int r = 0; r < 4; ++r) {
                uint2 v = *(const uint2*)(Wb + (size_t)jv[r] * N_HID);
                o4[r] += bf2f(Wo[(size_t)jv[r] * N_OUT]);
                a[r][0] += __uint_as_float(v.x << 16);
                a[r][1] += __uint_as_float(v.x & 0xFFFF0000u);
                a[r][2] += __uint_as_float(v.y << 16);
                a[r][3] += __uint_as_float(v.y & 0xFFFF0000u);
            }
        }
        for (; i < n2; ++i) {
            int j = list[i];
            uint2 v = *(const uint2*)(Wb + (size_t)j * N_HID);
            o4[0] += bf2f(Wo[(size_t)j * N_OUT]);
            a[0][0] += __uint_as_float(v.x << 16);
            a[0][1] += __uint_as_float(v.x & 0xFFFF0000u);
            a[0][2] += __uint_as_float(v.y << 16);
            a[0][3] += __uint_as_float(v.y & 0xFFFF0000u);
        }
        float oacc = (o4[0] + o4[1]) + (o4[2] + o4[3]);
        om = TAU * om + (inact ? (cso - oacc) : oacc);
        out[((size_t)b * T_SZ + (t0 + tloc0 + tl)) * N_OUT + t] = om;
        #pragma unroll
        for (int k = 0; k < 4; ++k) {
            float racc = (a[0][k] + a[1][k]) + (a[2][k] + a[3][k]);
            rec_cur[k] = REC_SCALE * (inact ? (csr[k] - racc) : racc);
        }

        if (more) ivq = iv_next;
    }

    #pragma unroll
    for (int k = 0; k < 4; ++k)
        h_mem_g[(size_t)b * N_HID + 4 * t + k] = hm[k];
    o_mem_g[(size_t)b * N_OUT + t] = om;
    __syncthreads();
    if (t < 64) mask_g[b * 64 + t] = mask[t];
}

// ---------------------------------------------------------------------------
extern "C" void kernel_launch(void* const* d_in, const int* in_sizes, int n_in,
                              void* d_out, int out_size, void* d_ws, size_t ws_size,
                              hipStream_t stream) {
    const float* x    = (const float*)d_in[0];
    const float* Wfc1 = (const float*)d_in[1];
    const float* Wrec = (const float*)d_in[2];
    const float* Wout = (const float*)d_in[3];
    float* out = (float*)d_out;

    // workspace layout (all 16B-aligned)
    float* h_mem = (float*)d_ws;                               // 2 MB
    float* o_mem = h_mem + B_SZ * N_HID;                       // 0.5 MB
    unsigned long long* maskg =
        (unsigned long long*)(o_mem + B_SZ * N_OUT);           // 64 KB
    float* cs_rec = (float*)(maskg + B_SZ * 64);               // 16 KB
    float* cs_out = cs_rec + N_HID;                            // 4 KB
    unsigned short* WrecB = (unsigned short*)(cs_out + N_OUT); // 33.55 MB
    unsigned short* WoutB = WrecB + (size_t)N_HID * N_HID;     // 8.39 MB
    unsigned short* WrecT = WoutB + (size_t)N_HID * N_OUT;     // 33.55 MB
    unsigned short* WoutT = WrecT + (size_t)N_HID * N_HID;     // 8.39 MB
    char* Bt = (char*)(WoutT + (size_t)N_OUT * N_HID);         // 8.39 MB (i8)
    unsigned short* spk = (unsigned short*)(Bt + (size_t)N_HID * 2048); // 1.05 MB
    float* rec_part = (float*)(spk + (size_t)B_SZ * N_HID);    // 16.78 MB
    float* out_part = rec_part + (size_t)KSPLIT * B_SZ * N_HID;// 4.19 MB
    char* Ax = (char*)(out_part + (size_t)KSPLIT * B_SZ * N_OUT);
    // inp_chunk follows Ax (Tc-dependent)

    size_t fixed_bytes = (size_t)(B_SZ * N_HID + B_SZ * N_OUT) * 4
                       + (size_t)B_SZ * 64 * 8
                       + (size_t)(N_HID + N_OUT) * 4
                       + 2 * (size_t)N_HID * N_HID * 2          // WrecB + WrecT
                       + 2 * (size_t)N_HID * N_OUT * 2          // WoutB + WoutT
                       + (size_t)N_HID * 2048                   // Bt (int8)
                       + (size_t)B_SZ * N_HID * 2               // spk
                       + (size_t)KSPLIT * B_SZ * (N_HID + N_OUT) * 4;
    int Tc = 64;
    while (Tc > 8 &&
           fixed_bytes + (size_t)Tc * (B_SZ * 2048 + B_SZ * N_HID * 4) > ws_size)
        Tc >>= 1;
    float* inp_chunk = (float*)(Ax + (size_t)B_SZ * Tc * 2048);

    int state_floats = B_SZ * N_HID + B_SZ * N_OUT + B_SZ * 64 * 2;
    zero_state_kernel<<<256, 256, 0, stream>>>(h_mem, state_floats);
    // fused bf16 copy + transpose (one read of each weight matrix)
    convT_bf16_kernel<<<dim3(N_HID / 64, N_HID / 64), 256, 0, stream>>>(
        Wrec, WrecB, WrecT, N_HID, N_HID);
    convT_bf16_kernel<<<dim3(N_OUT / 64, N_HID / 64), 256, 0, stream>>>(
        Wout, WoutB, WoutT, N_HID, N_OUT);
    colsum_bf16_kernel<<<80, 256, 0, stream>>>(WrecB, WoutB, cs_rec, cs_out);
    convert_w_kernel<<<dim3(32, 64), 256, 0, stream>>>(Wfc1, Bt);

    for (int t0 = 0; t0 < T_SZ; t0 += Tc) {
        convert_x_kernel<<<2048, 256, 0, stream>>>(x, Ax, t0, Tc);
        int my = (B_SZ * Tc) / 128;   // multiple of 8 for Tc >= 8
        fc1_mfma_kernel<<<32 * my, 256, 0, stream>>>(Ax, Bt, inp_chunk, my);

        if (t0 == 0) {
            // dense transient: steps 0..S_DENSE-1, two dispatches per step
            for (int tg = 0; tg < S_DENSE; ++tg) {
                transient_update_kernel<<<B_SZ * 4, 256, 0, stream>>>(
                    inp_chunk, rec_part, out_part, h_mem, o_mem, spk, maskg, out,
                    tg, Tc, /*has_rec=*/tg > 0, /*has_out=*/tg > 0);
                int do_rec = (tg + 1 < S_DENSE);
                spk_gemm_merged_kernel<<<do_rec ? 320 : 64, 256, 0, stream>>>(
                    spk, WrecT, WoutT, rec_part, out_part, do_rec);
            }
            rsnn_step_kernel<<<B_SZ, 1024, 0, stream>>>(
                inp_chunk, WrecB, WoutB, cs_rec, cs_out, out_part,
                h_mem, o_mem, maskg, out,
                t0, Tc, /*tloc0=*/S_DENSE, /*nsteps=*/Tc - S_DENSE, /*do_accum=*/1);
        } else {
            rsnn_step_kernel<<<B_SZ, 1024, 0, stream>>>(
                inp_chunk, WrecB, WoutB, cs_rec, cs_out, out_part,
                h_mem, o_mem, maskg, out,
                t0, Tc, /*tloc0=*/0, /*nsteps=*/Tc, /*do_accum=*/0);
        }
    }
}